// Round 12
// baseline (413.695 us; speedup 1.0000x reference)
//
#include <hip/hip_runtime.h>

typedef __bf16 bf16;
typedef __bf16 bf16x2 __attribute__((ext_vector_type(2)));
typedef __bf16 bf16x4 __attribute__((ext_vector_type(4)));
typedef __bf16 bf16x8 __attribute__((ext_vector_type(8)));
typedef float f32x4 __attribute__((ext_vector_type(4)));

typedef __attribute__((address_space(1))) const unsigned int gq_t;
typedef __attribute__((address_space(3))) unsigned int lq_t;

// ---------------------------------------------------------------------------
// fp32 -> bf16 converter, 8 elems/thread.
// ---------------------------------------------------------------------------
__global__ __launch_bounds__(256) void cvt_bf16(const float* __restrict__ in,
                                                bf16* __restrict__ out,
                                                int n8) {
  int i = blockIdx.x * 256 + threadIdx.x;
  if (i >= n8) return;
  f32x4 a = ((const f32x4*)in)[2 * i];
  f32x4 b = ((const f32x4*)in)[2 * i + 1];
  bf16x8 o;
#pragma unroll
  for (int j = 0; j < 4; ++j) {
    o[j] = (bf16)a[j];
    o[4 + j] = (bf16)b[j];
  }
  ((bf16x8*)out)[i] = o;
}

// ---------------------------------------------------------------------------
// 8-phase-style pipelined bf16 GEMM (T3+T4): 256x128 tile, BK=64, 512 thr
// (8 waves 2Mx4N), 3 LDS buffers (144 KB), counted vmcnt — never drains to 0
// in steady state. r11 showed the 2-phase ceiling (+7% only): __syncthreads'
// implicit vmcnt(0) drain each K-step is the documented 72% stall; counted
// vmcnt only pays inside a phase-interleaved schedule (m218: +38-73%).
// Hazard ledger:
//  - glds -> buf[(g+2)%3] issued in group g, AFTER the boundary barrier at
//    which that buffer's reads (group g-1) retired.
//  - ds_read of buf[g%3] covered by prev boundary: per-wave vmcnt(6) retires
//    all but tile g+2's 6 loads (in-order retirement, m135) + s_barrier for
//    cross-wave visibility.
//  - per phase: ds_read -> glds issue -> s_barrier -> lgkmcnt(0)+sched_barrier
//    (rule #18) -> setprio(1) 8 MFMA setprio(0) -> s_barrier.
//  - raw s_barrier (not __syncthreads) to avoid the forced vmcnt(0).
// Tail: last two groups wait vmcnt(0)/skip — epilogue drain is fine.
// ---------------------------------------------------------------------------
template <typename TC, bool ADD_BIAS>
__global__ __launch_bounds__(512) void gemm_8ph(const bf16* __restrict__ A,
                                                const bf16* __restrict__ B,
                                                const float* __restrict__ bias,
                                                TC* __restrict__ C,
                                                int M, int N, int K, int lda) {
  __shared__ __align__(16) bf16 As[3][256 * 64];  // 96 KB
  __shared__ __align__(16) bf16 Bs[3][128 * 64];  // 48 KB
  const int tid = threadIdx.x;
  const int lane = tid & 63;
  const int wid = tid >> 6;       // 0..7
  const int wm = wid >> 2;        // 0..1  (M half)
  const int wn = wid & 3;         // 0..3  (N quarter)
  const int m0 = blockIdx.y * 256;
  const int n0 = blockIdx.x * 128;
  const int l16 = lane & 15;
  const int lhi = lane >> 4;
  const int lr = lane >> 3;       // row within 8-row chunk
  const int lc = (lane & 7) * 8;  // col (elems) within row

  const int nkt = K >> 6;  // K-tiles (16 for K=1024)

  f32x4 acc[8][2] = {};

  auto stageA = [&](int kt, int buf, int u) {
    const int chunk = wid * 4 + u;  // 0..31, 8 rows x 64 cols each
    const int row = chunk * 8 + lr;
    const bf16* g = A + (size_t)(m0 + row) * lda + kt * 64 + lc;
    __builtin_amdgcn_global_load_lds((gq_t*)g, (lq_t*)&As[buf][chunk * 512],
                                     16, 0, 0);
  };
  auto stageB = [&](int kt, int buf, int u) {
    const int chunk = wid * 2 + u;  // 0..15
    const int row = chunk * 8 + lr;
    const bf16* g = B + (size_t)(n0 + row) * K + kt * 64 + lc;
    __builtin_amdgcn_global_load_lds((gq_t*)g, (lq_t*)&Bs[buf][chunk * 512],
                                     16, 0, 0);
  };

  // prologue: kt0 -> buf0 (6 glds), kt1 -> buf1 (6 glds); wait kt0 only.
  stageA(0, 0, 0); stageA(0, 0, 1); stageA(0, 0, 2); stageA(0, 0, 3);
  stageB(0, 0, 0); stageB(0, 0, 1);
  stageA(1, 1, 0); stageA(1, 1, 1); stageA(1, 1, 2); stageA(1, 1, 3);
  stageB(1, 1, 0); stageB(1, 1, 1);
  asm volatile("s_waitcnt vmcnt(6)" ::: "memory");
  __builtin_amdgcn_sched_barrier(0);
  __builtin_amdgcn_s_barrier();

  for (int g = 0; g < nkt; ++g) {
    const int buf = g % 3;
    const int nbuf = (g + 2) % 3;
    const bool donext = (g + 2) < nkt;
    const bf16* Asb = &As[buf][0];
    const bf16* Bsb = &Bs[buf][0];

#pragma unroll
    for (int q = 0; q < 4; ++q) {
      const int mh = q >> 1, nh = q & 1;
      // ds-read the quadrant's fragments (static indexing)
      bf16x8 af[4][2], bfn[2];
#pragma unroll
      for (int mf = 0; mf < 4; ++mf) {
        const int mrow = wm * 128 + (mh * 4 + mf) * 16 + l16;
#pragma unroll
        for (int ks = 0; ks < 2; ++ks)
          af[mf][ks] = *(const bf16x8*)(Asb + mrow * 64 + ks * 32 + lhi * 8);
      }
      {
        const int nrow = wn * 32 + nh * 16 + l16;
#pragma unroll
        for (int ks = 0; ks < 2; ++ks)
          bfn[ks] = *(const bf16x8*)(Bsb + nrow * 64 + ks * 32 + lhi * 8);
      }
      // stage-issue slot: spread tile g+2's 6 glds across the 4 phases
      if (donext) {
        if (q == 0) {
          stageA(g + 2, nbuf, 0);
          stageA(g + 2, nbuf, 1);
        } else if (q == 1) {
          stageA(g + 2, nbuf, 2);
          stageA(g + 2, nbuf, 3);
        } else if (q == 2) {
          stageB(g + 2, nbuf, 0);
        } else {
          stageB(g + 2, nbuf, 1);
        }
      }
      __builtin_amdgcn_s_barrier();
      asm volatile("s_waitcnt lgkmcnt(0)" ::: "memory");
      __builtin_amdgcn_sched_barrier(0);
      __builtin_amdgcn_s_setprio(1);
#pragma unroll
      for (int mf = 0; mf < 4; ++mf)
#pragma unroll
        for (int ks = 0; ks < 2; ++ks)
          acc[mh * 4 + mf][nh] = __builtin_amdgcn_mfma_f32_16x16x32_bf16(
              af[mf][ks], bfn[ks], acc[mh * 4 + mf][nh], 0, 0, 0);
      __builtin_amdgcn_s_setprio(0);
      __builtin_amdgcn_s_barrier();
    }

    // group boundary: tile g+1 must be landed for the next group's ds_reads.
    if (g + 1 < nkt) {
      if (donext) {
        asm volatile("s_waitcnt vmcnt(6)" ::: "memory");  // g+2's 6 in flight
      } else {
        asm volatile("s_waitcnt vmcnt(0)" ::: "memory");  // tail drain
      }
      __builtin_amdgcn_sched_barrier(0);
      __builtin_amdgcn_s_barrier();
    }
  }

  // epilogue: C write (per-wave 128x32 block, 8x2 fragments)
#pragma unroll
  for (int i = 0; i < 8; ++i) {
    int row_base = m0 + wm * 128 + i * 16 + lhi * 4;
#pragma unroll
    for (int j = 0; j < 2; ++j) {
      int col = n0 + wn * 32 + j * 16 + l16;
      float bv = ADD_BIAS ? bias[col] : 0.0f;
#pragma unroll
      for (int r = 0; r < 4; ++r) {
        float val = acc[i][j][r] + bv;
        if constexpr (__is_same(TC, float))
          C[(size_t)(row_base + r) * N + col] = val;
        else
          C[(size_t)(row_base + r) * N + col] = (bf16)val;
      }
    }
  }
}

// ---------------------------------------------------------------------------
// GEMM (legacy reg-staged, fp32 B): low-workspace fallback only.
// ---------------------------------------------------------------------------
template <typename TA, typename TC, bool ADD_BIAS>
__global__ __launch_bounds__(256) void gemm_bt(const TA* __restrict__ A,
                                               const float* __restrict__ B,
                                               const float* __restrict__ bias,
                                               TC* __restrict__ C,
                                               int M, int N, int K,
                                               int lda, int row0) {
  __shared__ __align__(16) bf16 As[128][72];
  __shared__ __align__(16) bf16 Bs[128][72];
  const int tid = threadIdx.x;
  const int lane = tid & 63;
  const int wid = tid >> 6;
  const int wr = wid >> 1, wc = wid & 1;
  const int m0 = blockIdx.y * 128;
  const int n0 = blockIdx.x * 128;
  const int l16 = lane & 15;
  const int lhi = lane >> 4;

  f32x4 acc[4][4] = {};

  for (int k0 = 0; k0 < K; k0 += 64) {
    __syncthreads();
#pragma unroll
    for (int p = 0; p < 8; ++p) {
      int v = tid + p * 256;
      int row = v >> 4;
      int kc = (v & 15) * 4;
      size_t ai = (size_t)(row0 + m0 + row) * lda + k0 + kc;
      size_t bi = (size_t)(n0 + row) * K + k0 + kc;
      bf16x4 ab, bb;
      if constexpr (__is_same(TA, float)) {
        f32x4 a4 = *(const f32x4*)((const float*)A + ai);
#pragma unroll
        for (int j = 0; j < 4; ++j) ab[j] = (bf16)a4[j];
      } else {
        ab = *(const bf16x4*)((const bf16*)A + ai);
      }
      f32x4 b4 = *(const f32x4*)(B + bi);
#pragma unroll
      for (int j = 0; j < 4; ++j) bb[j] = (bf16)b4[j];
      *(bf16x4*)(&As[row][kc]) = ab;
      *(bf16x4*)(&Bs[row][kc]) = bb;
    }
    __syncthreads();
#pragma unroll
    for (int ks = 0; ks < 2; ++ks) {
      bf16x8 af[4], bfr[4];
#pragma unroll
      for (int i = 0; i < 4; ++i) {
        af[i] = *(const bf16x8*)(&As[wr * 64 + i * 16 + l16][ks * 32 + lhi * 8]);
        bfr[i] = *(const bf16x8*)(&Bs[wc * 64 + i * 16 + l16][ks * 32 + lhi * 8]);
      }
#pragma unroll
      for (int i = 0; i < 4; ++i)
#pragma unroll
        for (int j = 0; j < 4; ++j)
          acc[i][j] = __builtin_amdgcn_mfma_f32_16x16x32_bf16(af[i], bfr[j],
                                                              acc[i][j], 0, 0, 0);
    }
  }

#pragma unroll
  for (int i = 0; i < 4; ++i) {
    int row_base = m0 + wr * 64 + i * 16 + lhi * 4;
#pragma unroll
    for (int j = 0; j < 4; ++j) {
      int col = n0 + wc * 64 + j * 16 + l16;
      float bv = ADD_BIAS ? bias[col] : 0.0f;
#pragma unroll
      for (int r = 0; r < 4; ++r) {
        float val = acc[i][j][r] + bv;
        if constexpr (__is_same(TC, float))
          C[(size_t)(row_base + r) * N + col] = val;
        else
          C[(size_t)(row_base + r) * N + col] = (bf16)val;
      }
    }
  }
}

// ---------------------------------------------------------------------------
// MFMA flash attention v8 (round-7 proven: 143 us; unchanged).
// ---------------------------------------------------------------------------
__global__ __launch_bounds__(256) void attn_fwd(bf16* __restrict__ qkv) {
  constexpr int S = 2048, D3 = 3072;
  constexpr float SCL = 0.18033688011112042f;  // 0.125 * log2(e)
  constexpr float THR = 11.5f;                 // 8 * log2(e)
  __shared__ __align__(16) bf16 Kt[2][64][72];  // [buf][key][dim]
  __shared__ __align__(16) bf16 Vt[2][64][72];  // [buf][dim][key]
  __shared__ __align__(16) bf16 Pq[4][16][72];  // per-wave transpose buffer

  const int tid = threadIdx.x;
  const int lane = tid & 63;
  const int wid = tid >> 6;
  const int l16 = lane & 15, lhi = lane >> 4;

  const int nwg = gridDim.x * gridDim.y;
  const int bid = blockIdx.y * gridDim.x + blockIdx.x;
  const int swz = (bid & 7) * (nwg >> 3) + (bid >> 3);
  const int bh = swz >> 4;
  const int b = bh >> 4, h = bh & 15;
  const int q0 = (swz & 15) * 128 + wid * 32;

  bf16* base = qkv + (size_t)b * S * D3;
  bf16* qbase = base + h * 64;
  const bf16* kbase = base + 1024 + h * 64;
  const bf16* vbase = base + 2048 + h * 64;

  bf16x8 qfA[2], qfB[2];
#pragma unroll
  for (int ks = 0; ks < 2; ++ks) {
    qfA[ks] = *(const bf16x8*)(qbase + (size_t)(q0 + l16) * D3 + ks * 32 + lhi * 8);
    qfB[ks] = *(const bf16x8*)(qbase + (size_t)(q0 + 16 + l16) * D3 + ks * 32 + lhi * 8);
  }

  float mA = -1e30f, mB = -1e30f;
  float lA = 0.0f, lB = 0.0f;
  f32x4 oA[4] = {}, oB[4] = {};

  const int kp = tid & 31, oc = tid >> 5;

  {
    bf16x8 k0 = *(const bf16x8*)(kbase + (size_t)(2 * kp) * D3 + oc * 8);
    bf16x8 k1 = *(const bf16x8*)(kbase + (size_t)(2 * kp + 1) * D3 + oc * 8);
    bf16x8 v0 = *(const bf16x8*)(vbase + (size_t)(2 * kp) * D3 + oc * 8);
    bf16x8 v1 = *(const bf16x8*)(vbase + (size_t)(2 * kp + 1) * D3 + oc * 8);
    *(bf16x8*)(&Kt[0][2 * kp][oc * 8]) = k0;
    *(bf16x8*)(&Kt[0][2 * kp + 1][oc * 8]) = k1;
#pragma unroll
    for (int j = 0; j < 8; ++j) {
      bf16x2 pr;
      pr[0] = v0[j];
      pr[1] = v1[j];
      *(bf16x2*)(&Vt[0][oc * 8 + j][2 * kp]) = pr;
    }
  }
  __syncthreads();

  for (int t = 0; t < S; t += 64) {
    const int cur = (t >> 6) & 1;
    const bool havenext = (t + 64 < S);

    bf16x8 kn0, kn1, vn0, vn1;
    if (havenext) {
      const bf16* kb = kbase + (size_t)(t + 64) * D3;
      const bf16* vb = vbase + (size_t)(t + 64) * D3;
      kn0 = *(const bf16x8*)(kb + (size_t)(2 * kp) * D3 + oc * 8);
      kn1 = *(const bf16x8*)(kb + (size_t)(2 * kp + 1) * D3 + oc * 8);
      vn0 = *(const bf16x8*)(vb + (size_t)(2 * kp) * D3 + oc * 8);
      vn1 = *(const bf16x8*)(vb + (size_t)(2 * kp + 1) * D3 + oc * 8);
    }

    f32x4 scA[4] = {}, scB[4] = {};
    __builtin_amdgcn_s_setprio(1);
#pragma unroll
    for (int ct = 0; ct < 4; ++ct) {
#pragma unroll
      for (int ks = 0; ks < 2; ++ks) {
        bf16x8 kf = *(const bf16x8*)(&Kt[cur][ct * 16 + l16][ks * 32 + lhi * 8]);
        scA[ct] = __builtin_amdgcn_mfma_f32_16x16x32_bf16(kf, qfA[ks], scA[ct], 0, 0, 0);
        scB[ct] = __builtin_amdgcn_mfma_f32_16x16x32_bf16(kf, qfB[ks], scB[ct], 0, 0, 0);
      }
    }
    __builtin_amdgcn_s_setprio(0);

    {
      float cm[4];
#pragma unroll
      for (int ct = 0; ct < 4; ++ct)
        cm[ct] = fmaxf(fmaxf(scA[ct][0], scA[ct][1]), fmaxf(scA[ct][2], scA[ct][3]));
      float mxs = fmaxf(fmaxf(cm[0], cm[1]), fmaxf(cm[2], cm[3])) * SCL;
      if (!__all(mxs - mA <= THR)) {
        float mw = mxs;
        mw = fmaxf(mw, __shfl_xor(mw, 16));
        mw = fmaxf(mw, __shfl_xor(mw, 32));
        float nm = fmaxf(mA, mw);
        float alpha = __builtin_amdgcn_exp2f(mA - nm);
        mA = nm;
        lA *= alpha;
#pragma unroll
        for (int dt = 0; dt < 4; ++dt)
#pragma unroll
          for (int r = 0; r < 4; ++r) oA[dt][r] *= alpha;
      }
      float rs4[4];
#pragma unroll
      for (int ct = 0; ct < 4; ++ct) {
#pragma unroll
        for (int r = 0; r < 4; ++r) {
          float p = __builtin_amdgcn_exp2f(__builtin_fmaf(scA[ct][r], SCL, -mA));
          scA[ct][r] = p;
        }
        rs4[ct] = (scA[ct][0] + scA[ct][1]) + (scA[ct][2] + scA[ct][3]);
      }
      lA += (rs4[0] + rs4[1]) + (rs4[2] + rs4[3]);
    }
#pragma unroll
    for (int ct = 0; ct < 4; ++ct) {
      bf16x4 pk;
#pragma unroll
      for (int r = 0; r < 4; ++r) pk[r] = (bf16)scA[ct][r];
      *(bf16x4*)(&Pq[wid][l16][ct * 16 + lhi * 4]) = pk;
    }
    bf16x8 pfA0 = *(const bf16x8*)(&Pq[wid][l16][lhi * 8]);
    bf16x8 pfA1 = *(const bf16x8*)(&Pq[wid][l16][32 + lhi * 8]);

    {
      float cm[4];
#pragma unroll
      for (int ct = 0; ct < 4; ++ct)
        cm[ct] = fmaxf(fmaxf(scB[ct][0], scB[ct][1]), fmaxf(scB[ct][2], scB[ct][3]));
      float mxs = fmaxf(fmaxf(cm[0], cm[1]), fmaxf(cm[2], cm[3])) * SCL;
      if (!__all(mxs - mB <= THR)) {
        float mw = mxs;
        mw = fmaxf(mw, __shfl_xor(mw, 16));
        mw = fmaxf(mw, __shfl_xor(mw, 32));
        float nm = fmaxf(mB, mw);
        float alpha = __builtin_amdgcn_exp2f(mB - nm);
        mB = nm;
        lB *= alpha;
#pragma unroll
        for (int dt = 0; dt < 4; ++dt)
#pragma unroll
          for (int r = 0; r < 4; ++r) oB[dt][r] *= alpha;
      }
      float rs4[4];
#pragma unroll
      for (int ct = 0; ct < 4; ++ct) {
#pragma unroll
        for (int r = 0; r < 4; ++r) {
          float p = __builtin_amdgcn_exp2f(__builtin_fmaf(scB[ct][r], SCL, -mB));
          scB[ct][r] = p;
        }
        rs4[ct] = (scB[ct][0] + scB[ct][1]) + (scB[ct][2] + scB[ct][3]);
      }
      lB += (rs4[0] + rs4[1]) + (rs4[2] + rs4[3]);
    }
#pragma unroll
    for (int ct = 0; ct < 4; ++ct) {
      bf16x4 pk;
#pragma unroll
      for (int r = 0; r < 4; ++r) pk[r] = (bf16)scB[ct][r];
      *(bf16x4*)(&Pq[wid][l16][ct * 16 + lhi * 4]) = pk;
    }
    bf16x8 pfB0 = *(const bf16x8*)(&Pq[wid][l16][lhi * 8]);
    bf16x8 pfB1 = *(const bf16x8*)(&Pq[wid][l16][32 + lhi * 8]);

    if (havenext) {
      *(bf16x8*)(&Kt[cur ^ 1][2 * kp][oc * 8]) = kn0;
      *(bf16x8*)(&Kt[cur ^ 1][2 * kp + 1][oc * 8]) = kn1;
#pragma unroll
      for (int j = 0; j < 8; ++j) {
        bf16x2 pr;
        pr[0] = vn0[j];
        pr[1] = vn1[j];
        *(bf16x2*)(&Vt[cur ^ 1][oc * 8 + j][2 * kp]) = pr;
      }
    }

    __builtin_amdgcn_s_setprio(1);
#pragma unroll
    for (int dt = 0; dt < 4; ++dt) {
      bf16x8 vf0 = *(const bf16x8*)(&Vt[cur][dt * 16 + l16][lhi * 8]);
      bf16x8 vf1 = *(const bf16x8*)(&Vt[cur][dt * 16 + l16][32 + lhi * 8]);
      oA[dt] = __builtin_amdgcn_mfma_f32_16x16x32_bf16(vf0, pfA0, oA[dt], 0, 0, 0);
      oA[dt] = __builtin_amdgcn_mfma_f32_16x16x32_bf16(vf1, pfA1, oA[dt], 0, 0, 0);
      oB[dt] = __builtin_amdgcn_mfma_f32_16x16x32_bf16(vf0, pfB0, oB[dt], 0, 0, 0);
      oB[dt] = __builtin_amdgcn_mfma_f32_16x16x32_bf16(vf1, pfB1, oB[dt], 0, 0, 0);
    }
    __builtin_amdgcn_s_setprio(0);

    __syncthreads();
  }

  {
    float l_i = lA;
    l_i += __shfl_xor(l_i, 16);
    l_i += __shfl_xor(l_i, 32);
    float rl = 1.0f / l_i;
#pragma unroll
    for (int dt = 0; dt < 4; ++dt) {
      bf16x4 ok;
#pragma unroll
      for (int r = 0; r < 4; ++r) ok[r] = (bf16)(oA[dt][r] * rl);
      *(bf16x4*)(&Pq[wid][l16][dt * 16 + lhi * 4]) = ok;
    }
    bf16x8 r0 = *(const bf16x8*)(&Pq[wid][l16][lhi * 16]);
    bf16x8 r1 = *(const bf16x8*)(&Pq[wid][l16][lhi * 16 + 8]);
    bf16* orow = qbase + (size_t)(q0 + l16) * D3 + lhi * 16;
    *(bf16x8*)(orow) = r0;
    *(bf16x8*)(orow + 8) = r1;
  }
  {
    float l_i = lB;
    l_i += __shfl_xor(l_i, 16);
    l_i += __shfl_xor(l_i, 32);
    float rl = 1.0f / l_i;
#pragma unroll
    for (int dt = 0; dt < 4; ++dt) {
      bf16x4 ok;
#pragma unroll
      for (int r = 0; r < 4; ++r) ok[r] = (bf16)(oB[dt][r] * rl);
      *(bf16x4*)(&Pq[wid][l16][dt * 16 + lhi * 4]) = ok;
    }
    bf16x8 r0 = *(const bf16x8*)(&Pq[wid][l16][lhi * 16]);
    bf16x8 r1 = *(const bf16x8*)(&Pq[wid][l16][lhi * 16 + 8]);
    bf16* orow = qbase + (size_t)(q0 + 16 + l16) * D3 + lhi * 16;
    *(bf16x8*)(orow) = r0;
    *(bf16x8*)(orow + 8) = r1;
  }
}

// ---------------------------------------------------------------------------
extern "C" void kernel_launch(void* const* d_in, const int* in_sizes, int n_in,
                              void* d_out, int out_size, void* d_ws,
                              size_t ws_size, hipStream_t stream) {
  constexpr int B = 4, S = 2048, D = 1024;

  const float* x = nullptr;
  const float* w_in = nullptr;
  const float* w_out = nullptr;
  const float* b_out = nullptr;
  for (int i = 0; i < n_in; ++i) {
    switch (in_sizes[i]) {
      case 8388608: x = (const float*)d_in[i]; break;
      case 3145728: w_in = (const float*)d_in[i]; break;
      case 1048576: w_out = (const float*)d_in[i]; break;
      case 1024: b_out = (const float*)d_in[i]; break;
    }
  }
  float* out = (float*)d_out;  // [4,2048,1024] fp32

  bf16* qkv = (bf16*)d_ws;
  const size_t need_full = (size_t)B * S * 3 * D * 2;      // 48 MiB (qkv)
  const size_t need_cvt = need_full +
                          ((size_t)B * S * D +              // x  bf16
                           (size_t)3 * D * D +              // w_in bf16
                           (size_t)D * D) * 2;              // w_out bf16

  if (ws_size >= need_cvt) {
    bf16* xb = qkv + (size_t)B * S * 3 * D;
    bf16* w_inb = xb + (size_t)B * S * D;
    bf16* w_outb = w_inb + (size_t)3 * D * D;
    const int nx8 = B * S * D / 8;
    const int nwi8 = 3 * D * D / 8;
    const int nwo8 = D * D / 8;
    cvt_bf16<<<dim3((nx8 + 255) / 256), 256, 0, stream>>>(x, xb, nx8);
    cvt_bf16<<<dim3((nwi8 + 255) / 256), 256, 0, stream>>>(w_in, w_inb, nwi8);
    cvt_bf16<<<dim3((nwo8 + 255) / 256), 256, 0, stream>>>(w_out, w_outb, nwo8);

    gemm_8ph<bf16, false><<<dim3(3 * D / 128, B * S / 256), 512, 0, stream>>>(
        xb, w_inb, nullptr, qkv, B * S, 3 * D, D, D);
    attn_fwd<<<dim3(S / 128, B * 16), 256, 0, stream>>>(qkv);
    gemm_8ph<float, true><<<dim3(D / 128, B * S / 256), 512, 0, stream>>>(
        qkv, w_outb, b_out, out, B * S, D, D, 3 * D);
  } else if (ws_size >= need_full) {
    gemm_bt<float, bf16, false><<<dim3(3 * D / 128, B * S / 128), 256, 0,
                                  stream>>>(x, w_in, nullptr, qkv, B * S,
                                            3 * D, D, D, 0);
    attn_fwd<<<dim3(S / 128, B * 16), 256, 0, stream>>>(qkv);
    gemm_bt<bf16, float, true><<<dim3(D / 128, B * S / 128), 256, 0, stream>>>(
        qkv, w_out, b_out, out, B * S, D, D, 3 * D, 0);
  } else {
    for (int b0 = 0; b0 < B; ++b0) {
      gemm_bt<float, bf16, false><<<dim3(3 * D / 128, S / 128), 256, 0,
                                    stream>>>(x, w_in, nullptr, qkv, S, 3 * D,
                                              D, D, b0 * S);
      attn_fwd<<<dim3(S / 128, 16), 256, 0, stream>>>(qkv);
      gemm_bt<bf16, float, true><<<dim3(D / 128, S / 128), 256, 0, stream>>>(
          qkv, w_out, b_out, out + (size_t)b0 * S * D, S, D, D, 3 * D, 0);
    }
  }
}

// Round 13
// 314.402 us; speedup vs baseline: 1.3158x; 1.3158x over previous
//
#include <hip/hip_runtime.h>

typedef __bf16 bf16;
typedef __bf16 bf16x2 __attribute__((ext_vector_type(2)));
typedef __bf16 bf16x4 __attribute__((ext_vector_type(4)));
typedef __bf16 bf16x8 __attribute__((ext_vector_type(8)));
typedef float f32x4 __attribute__((ext_vector_type(4)));

typedef __attribute__((address_space(1))) const unsigned int gq_t;
typedef __attribute__((address_space(3))) unsigned int lq_t;

// ---------------------------------------------------------------------------
// fp32 -> bf16 converter, 8 elems/thread.
// ---------------------------------------------------------------------------
__global__ __launch_bounds__(256) void cvt_bf16(const float* __restrict__ in,
                                                bf16* __restrict__ out,
                                                int n8) {
  int i = blockIdx.x * 256 + threadIdx.x;
  if (i >= n8) return;
  f32x4 a = ((const f32x4*)in)[2 * i];
  f32x4 b = ((const f32x4*)in)[2 * i + 1];
  bf16x8 o;
#pragma unroll
  for (int j = 0; j < 4; ++j) {
    o[j] = (bf16)a[j];
    o[4 + j] = (bf16)b[j];
  }
  ((bf16x8*)out)[i] = o;
}

// ---------------------------------------------------------------------------
// Pipelined bf16 GEMM v2 (T2+T3+T4): 256x128 tile, BK=64, 512 thr (8 waves
// 2Mx4N), 3 LDS buffers, counted vmcnt(6).
// r12 post-mortem: linear [row][64] LDS = 16-way bank conflict on ds_read_b128
// (row stride 128 B == 0 mod 32 banks; SQ_LDS_BANK_CONFLICT 4.7e7 — dominant).
// Fixes vs r12:
//  - T2 swizzle BOTH sides (rule #21): 16B slot s ^= (row&7). glds dest stays
//    LINEAR; the SOURCE global column is pre-swizzled ((lane&7)^lr), and the
//    ds_read address applies the same XOR. Bijective involution per 8-row
//    stripe; residual 2-way (free, m136).
//  - 2 phases per K-tile (16 MFMA each, template-matching), 5 barriers/K-tile
//    (was 9).
//  - bijective XCD swizzle on the block grid (nwg%8==0 both GEMMs).
// Hazard ledger unchanged from r12 (ran correct): glds->buf[(g+2)%3] after
// the boundary at which that buffer's reads retired; boundary waits vmcnt(6)
// (g+2's 6 loads in flight), never 0 in steady state; raw s_barrier only.
// ---------------------------------------------------------------------------
template <typename TC, bool ADD_BIAS>
__global__ __launch_bounds__(512) void gemm_8ph(const bf16* __restrict__ A,
                                                const bf16* __restrict__ B,
                                                const float* __restrict__ bias,
                                                TC* __restrict__ C,
                                                int M, int N, int K, int lda) {
  __shared__ __align__(16) bf16 As[3][256 * 64];  // 96 KB
  __shared__ __align__(16) bf16 Bs[3][128 * 64];  // 48 KB
  const int tid = threadIdx.x;
  const int lane = tid & 63;
  const int wid = tid >> 6;       // 0..7
  const int wm = wid >> 2;        // 0..1  (M half)
  const int wn = wid & 3;         // 0..3  (N quarter)
  const int l16 = lane & 15;
  const int lhi = lane >> 4;
  const int lr = lane >> 3;       // row within 8-row chunk (0..7)

  // bijective XCD swizzle (nwg: 768 / 256, both % 8 == 0)
  const int nwg = gridDim.x * gridDim.y;
  const int bid0 = blockIdx.y * gridDim.x + blockIdx.x;
  const int swzb = (bid0 & 7) * (nwg >> 3) + (bid0 >> 3);
  const int m0 = (swzb / gridDim.x) * 256;
  const int n0 = (swzb % gridDim.x) * 128;

  const int nkt = K >> 6;

  f32x4 acc[8][2] = {};

  // T2: source column pre-swizzled so linear glds dest yields swizzled LDS.
  auto stageA = [&](int kt, int buf, int u) {
    const int chunk = wid * 4 + u;  // 32 chunks of 8 rows x 64 cols
    const int row = chunk * 8 + lr;
    const int cs = (lane & 7) ^ lr;  // swizzled 16B slot
    const bf16* g = A + (size_t)(m0 + row) * lda + kt * 64 + cs * 8;
    __builtin_amdgcn_global_load_lds((gq_t*)g, (lq_t*)&As[buf][chunk * 512],
                                     16, 0, 0);
  };
  auto stageB = [&](int kt, int buf, int u) {
    const int chunk = wid * 2 + u;  // 16 chunks
    const int row = chunk * 8 + lr;
    const int cs = (lane & 7) ^ lr;
    const bf16* g = B + (size_t)(n0 + row) * K + kt * 64 + cs * 8;
    __builtin_amdgcn_global_load_lds((gq_t*)g, (lq_t*)&Bs[buf][chunk * 512],
                                     16, 0, 0);
  };

  // prologue: kt0 -> buf0, kt1 -> buf1; wait kt0's 6 only.
  stageA(0, 0, 0); stageA(0, 0, 1); stageA(0, 0, 2); stageA(0, 0, 3);
  stageB(0, 0, 0); stageB(0, 0, 1);
  stageA(1, 1, 0); stageA(1, 1, 1); stageA(1, 1, 2); stageA(1, 1, 3);
  stageB(1, 1, 0); stageB(1, 1, 1);
  asm volatile("s_waitcnt vmcnt(6)" ::: "memory");
  __builtin_amdgcn_sched_barrier(0);
  __builtin_amdgcn_s_barrier();

  for (int g = 0; g < nkt; ++g) {
    const int buf = g % 3;
    const int nbuf = (g + 2) % 3;
    const bool donext = (g + 2) < nkt;
    const bf16* Asb = &As[buf][0];
    const bf16* Bsb = &Bs[buf][0];

#pragma unroll
    for (int q = 0; q < 2; ++q) {  // two phases, 16 MFMA each
      bf16x8 af[4][2], bfn[2][2];
#pragma unroll
      for (int mf = 0; mf < 4; ++mf) {
        const int mrow = wm * 128 + (q * 4 + mf) * 16 + l16;
        const int sw = mrow & 7;
#pragma unroll
        for (int ks = 0; ks < 2; ++ks) {
          const int slot = ks * 4 + lhi;
          af[mf][ks] = *(const bf16x8*)(Asb + mrow * 64 + ((slot ^ sw) << 3));
        }
      }
#pragma unroll
      for (int nh = 0; nh < 2; ++nh) {
        const int nrow = wn * 32 + nh * 16 + l16;
        const int sw = nrow & 7;
#pragma unroll
        for (int ks = 0; ks < 2; ++ks) {
          const int slot = ks * 4 + lhi;
          bfn[nh][ks] = *(const bf16x8*)(Bsb + nrow * 64 + ((slot ^ sw) << 3));
        }
      }
      // stage-issue slot: tile g+2's 6 glds spread 3+3 over the 2 phases
      if (donext) {
        if (q == 0) {
          stageA(g + 2, nbuf, 0);
          stageA(g + 2, nbuf, 1);
          stageA(g + 2, nbuf, 2);
        } else {
          stageA(g + 2, nbuf, 3);
          stageB(g + 2, nbuf, 0);
          stageB(g + 2, nbuf, 1);
        }
      }
      __builtin_amdgcn_s_barrier();
      asm volatile("s_waitcnt lgkmcnt(0)" ::: "memory");
      __builtin_amdgcn_sched_barrier(0);
      __builtin_amdgcn_s_setprio(1);
#pragma unroll
      for (int mf = 0; mf < 4; ++mf)
#pragma unroll
        for (int nh = 0; nh < 2; ++nh)
#pragma unroll
          for (int ks = 0; ks < 2; ++ks)
            acc[q * 4 + mf][nh] = __builtin_amdgcn_mfma_f32_16x16x32_bf16(
                af[mf][ks], bfn[nh][ks], acc[q * 4 + mf][nh], 0, 0, 0);
      __builtin_amdgcn_s_setprio(0);
      __builtin_amdgcn_s_barrier();
    }

    // group boundary: tile g+1 must be landed for next group's ds_reads.
    if (g + 1 < nkt) {
      if (donext) {
        asm volatile("s_waitcnt vmcnt(6)" ::: "memory");
      } else {
        asm volatile("s_waitcnt vmcnt(0)" ::: "memory");
      }
      __builtin_amdgcn_sched_barrier(0);
      __builtin_amdgcn_s_barrier();
    }
  }

  // epilogue: per-wave 128x32 block, 8x2 fragments
#pragma unroll
  for (int i = 0; i < 8; ++i) {
    int row_base = m0 + wm * 128 + i * 16 + lhi * 4;
#pragma unroll
    for (int j = 0; j < 2; ++j) {
      int col = n0 + wn * 32 + j * 16 + l16;
      float bv = ADD_BIAS ? bias[col] : 0.0f;
#pragma unroll
      for (int r = 0; r < 4; ++r) {
        float val = acc[i][j][r] + bv;
        if constexpr (__is_same(TC, float))
          C[(size_t)(row_base + r) * N + col] = val;
        else
          C[(size_t)(row_base + r) * N + col] = (bf16)val;
      }
    }
  }
}

// ---------------------------------------------------------------------------
// GEMM (legacy reg-staged, fp32 B): low-workspace fallback only.
// ---------------------------------------------------------------------------
template <typename TA, typename TC, bool ADD_BIAS>
__global__ __launch_bounds__(256) void gemm_bt(const TA* __restrict__ A,
                                               const float* __restrict__ B,
                                               const float* __restrict__ bias,
                                               TC* __restrict__ C,
                                               int M, int N, int K,
                                               int lda, int row0) {
  __shared__ __align__(16) bf16 As[128][72];
  __shared__ __align__(16) bf16 Bs[128][72];
  const int tid = threadIdx.x;
  const int lane = tid & 63;
  const int wid = tid >> 6;
  const int wr = wid >> 1, wc = wid & 1;
  const int m0 = blockIdx.y * 128;
  const int n0 = blockIdx.x * 128;
  const int l16 = lane & 15;
  const int lhi = lane >> 4;

  f32x4 acc[4][4] = {};

  for (int k0 = 0; k0 < K; k0 += 64) {
    __syncthreads();
#pragma unroll
    for (int p = 0; p < 8; ++p) {
      int v = tid + p * 256;
      int row = v >> 4;
      int kc = (v & 15) * 4;
      size_t ai = (size_t)(row0 + m0 + row) * lda + k0 + kc;
      size_t bi = (size_t)(n0 + row) * K + k0 + kc;
      bf16x4 ab, bb;
      if constexpr (__is_same(TA, float)) {
        f32x4 a4 = *(const f32x4*)((const float*)A + ai);
#pragma unroll
        for (int j = 0; j < 4; ++j) ab[j] = (bf16)a4[j];
      } else {
        ab = *(const bf16x4*)((const bf16*)A + ai);
      }
      f32x4 b4 = *(const f32x4*)(B + bi);
#pragma unroll
      for (int j = 0; j < 4; ++j) bb[j] = (bf16)b4[j];
      *(bf16x4*)(&As[row][kc]) = ab;
      *(bf16x4*)(&Bs[row][kc]) = bb;
    }
    __syncthreads();
#pragma unroll
    for (int ks = 0; ks < 2; ++ks) {
      bf16x8 af[4], bfr[4];
#pragma unroll
      for (int i = 0; i < 4; ++i) {
        af[i] = *(const bf16x8*)(&As[wr * 64 + i * 16 + l16][ks * 32 + lhi * 8]);
        bfr[i] = *(const bf16x8*)(&Bs[wc * 64 + i * 16 + l16][ks * 32 + lhi * 8]);
      }
#pragma unroll
      for (int i = 0; i < 4; ++i)
#pragma unroll
        for (int j = 0; j < 4; ++j)
          acc[i][j] = __builtin_amdgcn_mfma_f32_16x16x32_bf16(af[i], bfr[j],
                                                              acc[i][j], 0, 0, 0);
    }
  }

#pragma unroll
  for (int i = 0; i < 4; ++i) {
    int row_base = m0 + wr * 64 + i * 16 + lhi * 4;
#pragma unroll
    for (int j = 0; j < 4; ++j) {
      int col = n0 + wc * 64 + j * 16 + l16;
      float bv = ADD_BIAS ? bias[col] : 0.0f;
#pragma unroll
      for (int r = 0; r < 4; ++r) {
        float val = acc[i][j][r] + bv;
        if constexpr (__is_same(TC, float))
          C[(size_t)(row_base + r) * N + col] = val;
        else
          C[(size_t)(row_base + r) * N + col] = (bf16)val;
      }
    }
  }
}

// ---------------------------------------------------------------------------
// MFMA flash attention v8 (round-7 proven: 143 us; unchanged).
// ---------------------------------------------------------------------------
__global__ __launch_bounds__(256) void attn_fwd(bf16* __restrict__ qkv) {
  constexpr int S = 2048, D3 = 3072;
  constexpr float SCL = 0.18033688011112042f;  // 0.125 * log2(e)
  constexpr float THR = 11.5f;                 // 8 * log2(e)
  __shared__ __align__(16) bf16 Kt[2][64][72];  // [buf][key][dim]
  __shared__ __align__(16) bf16 Vt[2][64][72];  // [buf][dim][key]
  __shared__ __align__(16) bf16 Pq[4][16][72];  // per-wave transpose buffer

  const int tid = threadIdx.x;
  const int lane = tid & 63;
  const int wid = tid >> 6;
  const int l16 = lane & 15, lhi = lane >> 4;

  const int nwg = gridDim.x * gridDim.y;
  const int bid = blockIdx.y * gridDim.x + blockIdx.x;
  const int swz = (bid & 7) * (nwg >> 3) + (bid >> 3);
  const int bh = swz >> 4;
  const int b = bh >> 4, h = bh & 15;
  const int q0 = (swz & 15) * 128 + wid * 32;

  bf16* base = qkv + (size_t)b * S * D3;
  bf16* qbase = base + h * 64;
  const bf16* kbase = base + 1024 + h * 64;
  const bf16* vbase = base + 2048 + h * 64;

  bf16x8 qfA[2], qfB[2];
#pragma unroll
  for (int ks = 0; ks < 2; ++ks) {
    qfA[ks] = *(const bf16x8*)(qbase + (size_t)(q0 + l16) * D3 + ks * 32 + lhi * 8);
    qfB[ks] = *(const bf16x8*)(qbase + (size_t)(q0 + 16 + l16) * D3 + ks * 32 + lhi * 8);
  }

  float mA = -1e30f, mB = -1e30f;
  float lA = 0.0f, lB = 0.0f;
  f32x4 oA[4] = {}, oB[4] = {};

  const int kp = tid & 31, oc = tid >> 5;

  {
    bf16x8 k0 = *(const bf16x8*)(kbase + (size_t)(2 * kp) * D3 + oc * 8);
    bf16x8 k1 = *(const bf16x8*)(kbase + (size_t)(2 * kp + 1) * D3 + oc * 8);
    bf16x8 v0 = *(const bf16x8*)(vbase + (size_t)(2 * kp) * D3 + oc * 8);
    bf16x8 v1 = *(const bf16x8*)(vbase + (size_t)(2 * kp + 1) * D3 + oc * 8);
    *(bf16x8*)(&Kt[0][2 * kp][oc * 8]) = k0;
    *(bf16x8*)(&Kt[0][2 * kp + 1][oc * 8]) = k1;
#pragma unroll
    for (int j = 0; j < 8; ++j) {
      bf16x2 pr;
      pr[0] = v0[j];
      pr[1] = v1[j];
      *(bf16x2*)(&Vt[0][oc * 8 + j][2 * kp]) = pr;
    }
  }
  __syncthreads();

  for (int t = 0; t < S; t += 64) {
    const int cur = (t >> 6) & 1;
    const bool havenext = (t + 64 < S);

    bf16x8 kn0, kn1, vn0, vn1;
    if (havenext) {
      const bf16* kb = kbase + (size_t)(t + 64) * D3;
      const bf16* vb = vbase + (size_t)(t + 64) * D3;
      kn0 = *(const bf16x8*)(kb + (size_t)(2 * kp) * D3 + oc * 8);
      kn1 = *(const bf16x8*)(kb + (size_t)(2 * kp + 1) * D3 + oc * 8);
      vn0 = *(const bf16x8*)(vb + (size_t)(2 * kp) * D3 + oc * 8);
      vn1 = *(const bf16x8*)(vb + (size_t)(2 * kp + 1) * D3 + oc * 8);
    }

    f32x4 scA[4] = {}, scB[4] = {};
    __builtin_amdgcn_s_setprio(1);
#pragma unroll
    for (int ct = 0; ct < 4; ++ct) {
#pragma unroll
      for (int ks = 0; ks < 2; ++ks) {
        bf16x8 kf = *(const bf16x8*)(&Kt[cur][ct * 16 + l16][ks * 32 + lhi * 8]);
        scA[ct] = __builtin_amdgcn_mfma_f32_16x16x32_bf16(kf, qfA[ks], scA[ct], 0, 0, 0);
        scB[ct] = __builtin_amdgcn_mfma_f32_16x16x32_bf16(kf, qfB[ks], scB[ct], 0, 0, 0);
      }
    }
    __builtin_amdgcn_s_setprio(0);

    {
      float cm[4];
#pragma unroll
      for (int ct = 0; ct < 4; ++ct)
        cm[ct] = fmaxf(fmaxf(scA[ct][0], scA[ct][1]), fmaxf(scA[ct][2], scA[ct][3]));
      float mxs = fmaxf(fmaxf(cm[0], cm[1]), fmaxf(cm[2], cm[3])) * SCL;
      if (!__all(mxs - mA <= THR)) {
        float mw = mxs;
        mw = fmaxf(mw, __shfl_xor(mw, 16));
        mw = fmaxf(mw, __shfl_xor(mw, 32));
        float nm = fmaxf(mA, mw);
        float alpha = __builtin_amdgcn_exp2f(mA - nm);
        mA = nm;
        lA *= alpha;
#pragma unroll
        for (int dt = 0; dt < 4; ++dt)
#pragma unroll
          for (int r = 0; r < 4; ++r) oA[dt][r] *= alpha;
      }
      float rs4[4];
#pragma unroll
      for (int ct = 0; ct < 4; ++ct) {
#pragma unroll
        for (int r = 0; r < 4; ++r) {
          float p = __builtin_amdgcn_exp2f(__builtin_fmaf(scA[ct][r], SCL, -mA));
          scA[ct][r] = p;
        }
        rs4[ct] = (scA[ct][0] + scA[ct][1]) + (scA[ct][2] + scA[ct][3]);
      }
      lA += (rs4[0] + rs4[1]) + (rs4[2] + rs4[3]);
    }
#pragma unroll
    for (int ct = 0; ct < 4; ++ct) {
      bf16x4 pk;
#pragma unroll
      for (int r = 0; r < 4; ++r) pk[r] = (bf16)scA[ct][r];
      *(bf16x4*)(&Pq[wid][l16][ct * 16 + lhi * 4]) = pk;
    }
    bf16x8 pfA0 = *(const bf16x8*)(&Pq[wid][l16][lhi * 8]);
    bf16x8 pfA1 = *(const bf16x8*)(&Pq[wid][l16][32 + lhi * 8]);

    {
      float cm[4];
#pragma unroll
      for (int ct = 0; ct < 4; ++ct)
        cm[ct] = fmaxf(fmaxf(scB[ct][0], scB[ct][1]), fmaxf(scB[ct][2], scB[ct][3]));
      float mxs = fmaxf(fmaxf(cm[0], cm[1]), fmaxf(cm[2], cm[3])) * SCL;
      if (!__all(mxs - mB <= THR)) {
        float mw = mxs;
        mw = fmaxf(mw, __shfl_xor(mw, 16));
        mw = fmaxf(mw, __shfl_xor(mw, 32));
        float nm = fmaxf(mB, mw);
        float alpha = __builtin_amdgcn_exp2f(mB - nm);
        mB = nm;
        lB *= alpha;
#pragma unroll
        for (int dt = 0; dt < 4; ++dt)
#pragma unroll
          for (int r = 0; r < 4; ++r) oB[dt][r] *= alpha;
      }
      float rs4[4];
#pragma unroll
      for (int ct = 0; ct < 4; ++ct) {
#pragma unroll
        for (int r = 0; r < 4; ++r) {
          float p = __builtin_amdgcn_exp2f(__builtin_fmaf(scB[ct][r], SCL, -mB));
          scB[ct][r] = p;
        }
        rs4[ct] = (scB[ct][0] + scB[ct][1]) + (scB[ct][2] + scB[ct][3]);
      }
      lB += (rs4[0] + rs4[1]) + (rs4[2] + rs4[3]);
    }
#pragma unroll
    for (int ct = 0; ct < 4; ++ct) {
      bf16x4 pk;
#pragma unroll
      for (int r = 0; r < 4; ++r) pk[r] = (bf16)scB[ct][r];
      *(bf16x4*)(&Pq[wid][l16][ct * 16 + lhi * 4]) = pk;
    }
    bf16x8 pfB0 = *(const bf16x8*)(&Pq[wid][l16][lhi * 8]);
    bf16x8 pfB1 = *(const bf16x8*)(&Pq[wid][l16][32 + lhi * 8]);

    if (havenext) {
      *(bf16x8*)(&Kt[cur ^ 1][2 * kp][oc * 8]) = kn0;
      *(bf16x8*)(&Kt[cur ^ 1][2 * kp + 1][oc * 8]) = kn1;
#pragma unroll
      for (int j = 0; j < 8; ++j) {
        bf16x2 pr;
        pr[0] = vn0[j];
        pr[1] = vn1[j];
        *(bf16x2*)(&Vt[cur ^ 1][oc * 8 + j][2 * kp]) = pr;
      }
    }

    __builtin_amdgcn_s_setprio(1);
#pragma unroll
    for (int dt = 0; dt < 4; ++dt) {
      bf16x8 vf0 = *(const bf16x8*)(&Vt[cur][dt * 16 + l16][lhi * 8]);
      bf16x8 vf1 = *(const bf16x8*)(&Vt[cur][dt * 16 + l16][32 + lhi * 8]);
      oA[dt] = __builtin_amdgcn_mfma_f32_16x16x32_bf16(vf0, pfA0, oA[dt], 0, 0, 0);
      oA[dt] = __builtin_amdgcn_mfma_f32_16x16x32_bf16(vf1, pfA1, oA[dt], 0, 0, 0);
      oB[dt] = __builtin_amdgcn_mfma_f32_16x16x32_bf16(vf0, pfB0, oB[dt], 0, 0, 0);
      oB[dt] = __builtin_amdgcn_mfma_f32_16x16x32_bf16(vf1, pfB1, oB[dt], 0, 0, 0);
    }
    __builtin_amdgcn_s_setprio(0);

    __syncthreads();
  }

  {
    float l_i = lA;
    l_i += __shfl_xor(l_i, 16);
    l_i += __shfl_xor(l_i, 32);
    float rl = 1.0f / l_i;
#pragma unroll
    for (int dt = 0; dt < 4; ++dt) {
      bf16x4 ok;
#pragma unroll
      for (int r = 0; r < 4; ++r) ok[r] = (bf16)(oA[dt][r] * rl);
      *(bf16x4*)(&Pq[wid][l16][dt * 16 + lhi * 4]) = ok;
    }
    bf16x8 r0 = *(const bf16x8*)(&Pq[wid][l16][lhi * 16]);
    bf16x8 r1 = *(const bf16x8*)(&Pq[wid][l16][lhi * 16 + 8]);
    bf16* orow = qbase + (size_t)(q0 + l16) * D3 + lhi * 16;
    *(bf16x8*)(orow) = r0;
    *(bf16x8*)(orow + 8) = r1;
  }
  {
    float l_i = lB;
    l_i += __shfl_xor(l_i, 16);
    l_i += __shfl_xor(l_i, 32);
    float rl = 1.0f / l_i;
#pragma unroll
    for (int dt = 0; dt < 4; ++dt) {
      bf16x4 ok;
#pragma unroll
      for (int r = 0; r < 4; ++r) ok[r] = (bf16)(oB[dt][r] * rl);
      *(bf16x4*)(&Pq[wid][l16][dt * 16 + lhi * 4]) = ok;
    }
    bf16x8 r0 = *(const bf16x8*)(&Pq[wid][l16][lhi * 16]);
    bf16x8 r1 = *(const bf16x8*)(&Pq[wid][l16][lhi * 16 + 8]);
    bf16* orow = qbase + (size_t)(q0 + 16 + l16) * D3 + lhi * 16;
    *(bf16x8*)(orow) = r0;
    *(bf16x8*)(orow + 8) = r1;
  }
}

// ---------------------------------------------------------------------------
extern "C" void kernel_launch(void* const* d_in, const int* in_sizes, int n_in,
                              void* d_out, int out_size, void* d_ws,
                              size_t ws_size, hipStream_t stream) {
  constexpr int B = 4, S = 2048, D = 1024;

  const float* x = nullptr;
  const float* w_in = nullptr;
  const float* w_out = nullptr;
  const float* b_out = nullptr;
  for (int i = 0; i < n_in; ++i) {
    switch (in_sizes[i]) {
      case 8388608: x = (const float*)d_in[i]; break;
      case 3145728: w_in = (const float*)d_in[i]; break;
      case 1048576: w_out = (const float*)d_in[i]; break;
      case 1024: b_out = (const float*)d_in[i]; break;
    }
  }
  float* out = (float*)d_out;  // [4,2048,1024] fp32

  bf16* qkv = (bf16*)d_ws;
  const size_t need_full = (size_t)B * S * 3 * D * 2;      // 48 MiB (qkv)
  const size_t need_cvt = need_full +
                          ((size_t)B * S * D +              // x  bf16
                           (size_t)3 * D * D +              // w_in bf16
                           (size_t)D * D) * 2;              // w_out bf16

  if (ws_size >= need_cvt) {
    bf16* xb = qkv + (size_t)B * S * 3 * D;
    bf16* w_inb = xb + (size_t)B * S * D;
    bf16* w_outb = w_inb + (size_t)3 * D * D;
    const int nx8 = B * S * D / 8;
    const int nwi8 = 3 * D * D / 8;
    const int nwo8 = D * D / 8;
    cvt_bf16<<<dim3((nx8 + 255) / 256), 256, 0, stream>>>(x, xb, nx8);
    cvt_bf16<<<dim3((nwi8 + 255) / 256), 256, 0, stream>>>(w_in, w_inb, nwi8);
    cvt_bf16<<<dim3((nwo8 + 255) / 256), 256, 0, stream>>>(w_out, w_outb, nwo8);

    gemm_8ph<bf16, false><<<dim3(3 * D / 128, B * S / 256), 512, 0, stream>>>(
        xb, w_inb, nullptr, qkv, B * S, 3 * D, D, D);
    attn_fwd<<<dim3(S / 128, B * 16), 256, 0, stream>>>(qkv);
    gemm_8ph<float, true><<<dim3(D / 128, B * S / 256), 512, 0, stream>>>(
        qkv, w_outb, b_out, out, B * S, D, D, 3 * D);
  } else if (ws_size >= need_full) {
    gemm_bt<float, bf16, false><<<dim3(3 * D / 128, B * S / 128), 256, 0,
                                  stream>>>(x, w_in, nullptr, qkv, B * S,
                                            3 * D, D, D, 0);
    attn_fwd<<<dim3(S / 128, B * 16), 256, 0, stream>>>(qkv);
    gemm_bt<bf16, float, true><<<dim3(D / 128, B * S / 128), 256, 0, stream>>>(
        qkv, w_out, b_out, out, B * S, D, D, 3 * D, 0);
  } else {
    for (int b0 = 0; b0 < B; ++b0) {
      gemm_bt<float, bf16, false><<<dim3(3 * D / 128, S / 128), 256, 0,
                                    stream>>>(x, w_in, nullptr, qkv, S, 3 * D,
                                              D, D, b0 * S);
      attn_fwd<<<dim3(S / 128, 16), 256, 0, stream>>>(qkv);
      gemm_bt<bf16, float, true><<<dim3(D / 128, S / 128), 256, 0, stream>>>(
          qkv, w_out, b_out, out + (size_t)b0 * S * D, S, D, D, 3 * D, 0);
    }
  }
}

// Round 14
// 293.099 us; speedup vs baseline: 1.4114x; 1.0727x over previous
//
#include <hip/hip_runtime.h>

typedef __bf16 bf16;
typedef __bf16 bf16x2 __attribute__((ext_vector_type(2)));
typedef __bf16 bf16x4 __attribute__((ext_vector_type(4)));
typedef __bf16 bf16x8 __attribute__((ext_vector_type(8)));
typedef float f32x4 __attribute__((ext_vector_type(4)));

typedef __attribute__((address_space(1))) const unsigned int gq_t;
typedef __attribute__((address_space(3))) unsigned int lq_t;

// ---------------------------------------------------------------------------
// fp32 -> bf16 converter, 8 elems/thread.
// ---------------------------------------------------------------------------
__global__ __launch_bounds__(256) void cvt_bf16(const float* __restrict__ in,
                                                bf16* __restrict__ out,
                                                int n8) {
  int i = blockIdx.x * 256 + threadIdx.x;
  if (i >= n8) return;
  f32x4 a = ((const f32x4*)in)[2 * i];
  f32x4 b = ((const f32x4*)in)[2 * i + 1];
  bf16x8 o;
#pragma unroll
  for (int j = 0; j < 4; ++j) {
    o[j] = (bf16)a[j];
    o[4 + j] = (bf16)b[j];
  }
  ((bf16x8*)out)[i] = o;
}

// ---------------------------------------------------------------------------
// Pipelined bf16 GEMM (T2+T3+T4), r13 measured: combined GEMMs ~158 us —
// equal to the 2-phase within noise; swizzle fixed the r12 conflict collapse
// (4.7e7 -> resolved). Two structures plateau at this short-K shape; PARKED.
// ---------------------------------------------------------------------------
template <typename TC, bool ADD_BIAS>
__global__ __launch_bounds__(512) void gemm_8ph(const bf16* __restrict__ A,
                                                const bf16* __restrict__ B,
                                                const float* __restrict__ bias,
                                                TC* __restrict__ C,
                                                int M, int N, int K, int lda) {
  __shared__ __align__(16) bf16 As[3][256 * 64];  // 96 KB
  __shared__ __align__(16) bf16 Bs[3][128 * 64];  // 48 KB
  const int tid = threadIdx.x;
  const int lane = tid & 63;
  const int wid = tid >> 6;       // 0..7
  const int wm = wid >> 2;        // 0..1  (M half)
  const int wn = wid & 3;         // 0..3  (N quarter)
  const int l16 = lane & 15;
  const int lhi = lane >> 4;
  const int lr = lane >> 3;       // row within 8-row chunk (0..7)

  const int nwg = gridDim.x * gridDim.y;
  const int bid0 = blockIdx.y * gridDim.x + blockIdx.x;
  const int swzb = (bid0 & 7) * (nwg >> 3) + (bid0 >> 3);
  const int m0 = (swzb / gridDim.x) * 256;
  const int n0 = (swzb % gridDim.x) * 128;

  const int nkt = K >> 6;

  f32x4 acc[8][2] = {};

  auto stageA = [&](int kt, int buf, int u) {
    const int chunk = wid * 4 + u;
    const int row = chunk * 8 + lr;
    const int cs = (lane & 7) ^ lr;  // T2 pre-swizzled source slot
    const bf16* g = A + (size_t)(m0 + row) * lda + kt * 64 + cs * 8;
    __builtin_amdgcn_global_load_lds((gq_t*)g, (lq_t*)&As[buf][chunk * 512],
                                     16, 0, 0);
  };
  auto stageB = [&](int kt, int buf, int u) {
    const int chunk = wid * 2 + u;
    const int row = chunk * 8 + lr;
    const int cs = (lane & 7) ^ lr;
    const bf16* g = B + (size_t)(n0 + row) * K + kt * 64 + cs * 8;
    __builtin_amdgcn_global_load_lds((gq_t*)g, (lq_t*)&Bs[buf][chunk * 512],
                                     16, 0, 0);
  };

  stageA(0, 0, 0); stageA(0, 0, 1); stageA(0, 0, 2); stageA(0, 0, 3);
  stageB(0, 0, 0); stageB(0, 0, 1);
  stageA(1, 1, 0); stageA(1, 1, 1); stageA(1, 1, 2); stageA(1, 1, 3);
  stageB(1, 1, 0); stageB(1, 1, 1);
  asm volatile("s_waitcnt vmcnt(6)" ::: "memory");
  __builtin_amdgcn_sched_barrier(0);
  __builtin_amdgcn_s_barrier();

  for (int g = 0; g < nkt; ++g) {
    const int buf = g % 3;
    const int nbuf = (g + 2) % 3;
    const bool donext = (g + 2) < nkt;
    const bf16* Asb = &As[buf][0];
    const bf16* Bsb = &Bs[buf][0];

#pragma unroll
    for (int q = 0; q < 2; ++q) {
      bf16x8 af[4][2], bfn[2][2];
#pragma unroll
      for (int mf = 0; mf < 4; ++mf) {
        const int mrow = wm * 128 + (q * 4 + mf) * 16 + l16;
        const int sw = mrow & 7;
#pragma unroll
        for (int ks = 0; ks < 2; ++ks) {
          const int slot = ks * 4 + lhi;
          af[mf][ks] = *(const bf16x8*)(Asb + mrow * 64 + ((slot ^ sw) << 3));
        }
      }
#pragma unroll
      for (int nh = 0; nh < 2; ++nh) {
        const int nrow = wn * 32 + nh * 16 + l16;
        const int sw = nrow & 7;
#pragma unroll
        for (int ks = 0; ks < 2; ++ks) {
          const int slot = ks * 4 + lhi;
          bfn[nh][ks] = *(const bf16x8*)(Bsb + nrow * 64 + ((slot ^ sw) << 3));
        }
      }
      if (donext) {
        if (q == 0) {
          stageA(g + 2, nbuf, 0);
          stageA(g + 2, nbuf, 1);
          stageA(g + 2, nbuf, 2);
        } else {
          stageA(g + 2, nbuf, 3);
          stageB(g + 2, nbuf, 0);
          stageB(g + 2, nbuf, 1);
        }
      }
      __builtin_amdgcn_s_barrier();
      asm volatile("s_waitcnt lgkmcnt(0)" ::: "memory");
      __builtin_amdgcn_sched_barrier(0);
      __builtin_amdgcn_s_setprio(1);
#pragma unroll
      for (int mf = 0; mf < 4; ++mf)
#pragma unroll
        for (int nh = 0; nh < 2; ++nh)
#pragma unroll
          for (int ks = 0; ks < 2; ++ks)
            acc[q * 4 + mf][nh] = __builtin_amdgcn_mfma_f32_16x16x32_bf16(
                af[mf][ks], bfn[nh][ks], acc[q * 4 + mf][nh], 0, 0, 0);
      __builtin_amdgcn_s_setprio(0);
      __builtin_amdgcn_s_barrier();
    }

    if (g + 1 < nkt) {
      if (donext) {
        asm volatile("s_waitcnt vmcnt(6)" ::: "memory");
      } else {
        asm volatile("s_waitcnt vmcnt(0)" ::: "memory");
      }
      __builtin_amdgcn_sched_barrier(0);
      __builtin_amdgcn_s_barrier();
    }
  }

#pragma unroll
  for (int i = 0; i < 8; ++i) {
    int row_base = m0 + wm * 128 + i * 16 + lhi * 4;
#pragma unroll
    for (int j = 0; j < 2; ++j) {
      int col = n0 + wn * 32 + j * 16 + l16;
      float bv = ADD_BIAS ? bias[col] : 0.0f;
#pragma unroll
      for (int r = 0; r < 4; ++r) {
        float val = acc[i][j][r] + bv;
        if constexpr (__is_same(TC, float))
          C[(size_t)(row_base + r) * N + col] = val;
        else
          C[(size_t)(row_base + r) * N + col] = (bf16)val;
      }
    }
  }
}

// ---------------------------------------------------------------------------
// GEMM (legacy reg-staged, fp32 B): low-workspace fallback only.
// ---------------------------------------------------------------------------
template <typename TA, typename TC, bool ADD_BIAS>
__global__ __launch_bounds__(256) void gemm_bt(const TA* __restrict__ A,
                                               const float* __restrict__ B,
                                               const float* __restrict__ bias,
                                               TC* __restrict__ C,
                                               int M, int N, int K,
                                               int lda, int row0) {
  __shared__ __align__(16) bf16 As[128][72];
  __shared__ __align__(16) bf16 Bs[128][72];
  const int tid = threadIdx.x;
  const int lane = tid & 63;
  const int wid = tid >> 6;
  const int wr = wid >> 1, wc = wid & 1;
  const int m0 = blockIdx.y * 128;
  const int n0 = blockIdx.x * 128;
  const int l16 = lane & 15;
  const int lhi = lane >> 4;

  f32x4 acc[4][4] = {};

  for (int k0 = 0; k0 < K; k0 += 64) {
    __syncthreads();
#pragma unroll
    for (int p = 0; p < 8; ++p) {
      int v = tid + p * 256;
      int row = v >> 4;
      int kc = (v & 15) * 4;
      size_t ai = (size_t)(row0 + m0 + row) * lda + k0 + kc;
      size_t bi = (size_t)(n0 + row) * K + k0 + kc;
      bf16x4 ab, bb;
      if constexpr (__is_same(TA, float)) {
        f32x4 a4 = *(const f32x4*)((const float*)A + ai);
#pragma unroll
        for (int j = 0; j < 4; ++j) ab[j] = (bf16)a4[j];
      } else {
        ab = *(const bf16x4*)((const bf16*)A + ai);
      }
      f32x4 b4 = *(const f32x4*)(B + bi);
#pragma unroll
      for (int j = 0; j < 4; ++j) bb[j] = (bf16)b4[j];
      *(bf16x4*)(&As[row][kc]) = ab;
      *(bf16x4*)(&Bs[row][kc]) = bb;
    }
    __syncthreads();
#pragma unroll
    for (int ks = 0; ks < 2; ++ks) {
      bf16x8 af[4], bfr[4];
#pragma unroll
      for (int i = 0; i < 4; ++i) {
        af[i] = *(const bf16x8*)(&As[wr * 64 + i * 16 + l16][ks * 32 + lhi * 8]);
        bfr[i] = *(const bf16x8*)(&Bs[wc * 64 + i * 16 + l16][ks * 32 + lhi * 8]);
      }
#pragma unroll
      for (int i = 0; i < 4; ++i)
#pragma unroll
        for (int j = 0; j < 4; ++j)
          acc[i][j] = __builtin_amdgcn_mfma_f32_16x16x32_bf16(af[i], bfr[j],
                                                              acc[i][j], 0, 0, 0);
    }
  }

#pragma unroll
  for (int i = 0; i < 4; ++i) {
    int row_base = m0 + wr * 64 + i * 16 + lhi * 4;
#pragma unroll
    for (int j = 0; j < 4; ++j) {
      int col = n0 + wc * 64 + j * 16 + l16;
      float bv = ADD_BIAS ? bias[col] : 0.0f;
#pragma unroll
      for (int r = 0; r < 4; ++r) {
        float val = acc[i][j][r] + bv;
        if constexpr (__is_same(TC, float))
          C[(size_t)(row_base + r) * N + col] = val;
        else
          C[(size_t)(row_base + r) * N + col] = (bf16)val;
      }
    }
  }
}

// ---------------------------------------------------------------------------
// MFMA flash attention v10: 8 waves/block (512 thr), ONE shared Kt/Vt stage.
//  - r13 diagnosis: occupancy 24.9% = 8 waves/CU; serial softmax chain can't
//    be hidden with 2 waves/SIMD. Per-wave structure is the r7-proven optimum
//    (32 rows, 2 sub-tiles) — unchanged. Change: 8 waves share one K/V tile,
//    waves 0-3 stage K, waves 4-7 stage V (sg wave-uniform; prefetch regs
//    halve). LDS 55 KB -> 2 blocks x 8 waves = 16 waves/CU (50%).
//  - Per-block staging traffic halves again; block count 1024 -> 512.
//  - Sync: identical single-barrier parity scheme (writes to cur^1 in iter t
//    race nothing; iter t+1's writes to cur are fenced by iter t's barrier).
// ---------------------------------------------------------------------------
__global__ __launch_bounds__(512) void attn_fwd(bf16* __restrict__ qkv) {
  constexpr int S = 2048, D3 = 3072;
  constexpr float SCL = 0.18033688011112042f;  // 0.125 * log2(e)
  constexpr float THR = 11.5f;                 // 8 * log2(e)
  __shared__ __align__(16) bf16 Kt[2][64][72];  // [buf][key][dim]
  __shared__ __align__(16) bf16 Vt[2][64][72];  // [buf][dim][key]
  __shared__ __align__(16) bf16 Pq[8][16][72];  // per-wave transpose buffer

  const int tid = threadIdx.x;
  const int lane = tid & 63;
  const int wid = tid >> 6;  // 0..7
  const int l16 = lane & 15, lhi = lane >> 4;

  // XCD-aware bijective swizzle (nwg % 8 == 0 in all launch paths).
  const int nwg = gridDim.x * gridDim.y;  // 512 (full) / 128 (fallback)
  const int bid = blockIdx.y * gridDim.x + blockIdx.x;
  const int swz = (bid & 7) * (nwg >> 3) + (bid >> 3);
  const int bh = swz >> 3;                // 8 q-tiles (256 rows) per bh
  const int b = bh >> 4, h = bh & 15;
  const int q0 = (swz & 7) * 256 + wid * 32;  // wave owns rows q0..q0+31

  bf16* base = qkv + (size_t)b * S * D3;
  bf16* qbase = base + h * 64;
  const bf16* kbase = base + 1024 + h * 64;
  const bf16* vbase = base + 2048 + h * 64;

  bf16x8 qfA[2], qfB[2];
#pragma unroll
  for (int ks = 0; ks < 2; ++ks) {
    qfA[ks] = *(const bf16x8*)(qbase + (size_t)(q0 + l16) * D3 + ks * 32 + lhi * 8);
    qfB[ks] = *(const bf16x8*)(qbase + (size_t)(q0 + 16 + l16) * D3 + ks * 32 + lhi * 8);
  }

  float mA = -1e30f, mB = -1e30f;
  float lA = 0.0f, lB = 0.0f;
  f32x4 oA[4] = {}, oB[4] = {};

  // staging split: waves 0-3 stage K, waves 4-7 stage V (wave-uniform)
  const int sg = tid >> 8;          // 0: K, 1: V
  const int kp = tid & 31;          // key pair 2kp, 2kp+1
  const int oc = (tid >> 5) & 7;    // dim octet

  const bf16* sbase = (sg == 0) ? kbase : vbase;

  // prologue: stage K(0) / V(0) into buffer 0
  {
    bf16x8 s0 = *(const bf16x8*)(sbase + (size_t)(2 * kp) * D3 + oc * 8);
    bf16x8 s1 = *(const bf16x8*)(sbase + (size_t)(2 * kp + 1) * D3 + oc * 8);
    if (sg == 0) {
      *(bf16x8*)(&Kt[0][2 * kp][oc * 8]) = s0;
      *(bf16x8*)(&Kt[0][2 * kp + 1][oc * 8]) = s1;
    } else {
#pragma unroll
      for (int j = 0; j < 8; ++j) {
        bf16x2 pr;
        pr[0] = s0[j];
        pr[1] = s1[j];
        *(bf16x2*)(&Vt[0][oc * 8 + j][2 * kp]) = pr;
      }
    }
  }
  __syncthreads();

  for (int t = 0; t < S; t += 64) {
    const int cur = (t >> 6) & 1;
    const bool havenext = (t + 64 < S);

    // issue next tile's loads FIRST (each wave stages only K or V: 8 VGPR)
    bf16x8 n0r, n1r;
    if (havenext) {
      const bf16* sb = sbase + (size_t)(t + 64) * D3;
      n0r = *(const bf16x8*)(sb + (size_t)(2 * kp) * D3 + oc * 8);
      n1r = *(const bf16x8*)(sb + (size_t)(2 * kp + 1) * D3 + oc * 8);
    }

    f32x4 scA[4] = {}, scB[4] = {};
    __builtin_amdgcn_s_setprio(1);
#pragma unroll
    for (int ct = 0; ct < 4; ++ct) {
#pragma unroll
      for (int ks = 0; ks < 2; ++ks) {
        bf16x8 kf = *(const bf16x8*)(&Kt[cur][ct * 16 + l16][ks * 32 + lhi * 8]);
        scA[ct] = __builtin_amdgcn_mfma_f32_16x16x32_bf16(kf, qfA[ks], scA[ct], 0, 0, 0);
        scB[ct] = __builtin_amdgcn_mfma_f32_16x16x32_bf16(kf, qfB[ks], scB[ct], 0, 0, 0);
      }
    }
    __builtin_amdgcn_s_setprio(0);

    {
      float cm[4];
#pragma unroll
      for (int ct = 0; ct < 4; ++ct)
        cm[ct] = fmaxf(fmaxf(scA[ct][0], scA[ct][1]), fmaxf(scA[ct][2], scA[ct][3]));
      float mxs = fmaxf(fmaxf(cm[0], cm[1]), fmaxf(cm[2], cm[3])) * SCL;
      if (!__all(mxs - mA <= THR)) {
        float mw = mxs;
        mw = fmaxf(mw, __shfl_xor(mw, 16));
        mw = fmaxf(mw, __shfl_xor(mw, 32));
        float nm = fmaxf(mA, mw);
        float alpha = __builtin_amdgcn_exp2f(mA - nm);
        mA = nm;
        lA *= alpha;
#pragma unroll
        for (int dt = 0; dt < 4; ++dt)
#pragma unroll
          for (int r = 0; r < 4; ++r) oA[dt][r] *= alpha;
      }
      float rs4[4];
#pragma unroll
      for (int ct = 0; ct < 4; ++ct) {
#pragma unroll
        for (int r = 0; r < 4; ++r) {
          float p = __builtin_amdgcn_exp2f(__builtin_fmaf(scA[ct][r], SCL, -mA));
          scA[ct][r] = p;
        }
        rs4[ct] = (scA[ct][0] + scA[ct][1]) + (scA[ct][2] + scA[ct][3]);
      }
      lA += (rs4[0] + rs4[1]) + (rs4[2] + rs4[3]);
    }
#pragma unroll
    for (int ct = 0; ct < 4; ++ct) {
      bf16x4 pk;
#pragma unroll
      for (int r = 0; r < 4; ++r) pk[r] = (bf16)scA[ct][r];
      *(bf16x4*)(&Pq[wid][l16][ct * 16 + lhi * 4]) = pk;
    }
    bf16x8 pfA0 = *(const bf16x8*)(&Pq[wid][l16][lhi * 8]);
    bf16x8 pfA1 = *(const bf16x8*)(&Pq[wid][l16][32 + lhi * 8]);

    {
      float cm[4];
#pragma unroll
      for (int ct = 0; ct < 4; ++ct)
        cm[ct] = fmaxf(fmaxf(scB[ct][0], scB[ct][1]), fmaxf(scB[ct][2], scB[ct][3]));
      float mxs = fmaxf(fmaxf(cm[0], cm[1]), fmaxf(cm[2], cm[3])) * SCL;
      if (!__all(mxs - mB <= THR)) {
        float mw = mxs;
        mw = fmaxf(mw, __shfl_xor(mw, 16));
        mw = fmaxf(mw, __shfl_xor(mw, 32));
        float nm = fmaxf(mB, mw);
        float alpha = __builtin_amdgcn_exp2f(mB - nm);
        mB = nm;
        lB *= alpha;
#pragma unroll
        for (int dt = 0; dt < 4; ++dt)
#pragma unroll
          for (int r = 0; r < 4; ++r) oB[dt][r] *= alpha;
      }
      float rs4[4];
#pragma unroll
      for (int ct = 0; ct < 4; ++ct) {
#pragma unroll
        for (int r = 0; r < 4; ++r) {
          float p = __builtin_amdgcn_exp2f(__builtin_fmaf(scB[ct][r], SCL, -mB));
          scB[ct][r] = p;
        }
        rs4[ct] = (scB[ct][0] + scB[ct][1]) + (scB[ct][2] + scB[ct][3]);
      }
      lB += (rs4[0] + rs4[1]) + (rs4[2] + rs4[3]);
    }
#pragma unroll
    for (int ct = 0; ct < 4; ++ct) {
      bf16x4 pk;
#pragma unroll
      for (int r = 0; r < 4; ++r) pk[r] = (bf16)scB[ct][r];
      *(bf16x4*)(&Pq[wid][l16][ct * 16 + lhi * 4]) = pk;
    }
    bf16x8 pfB0 = *(const bf16x8*)(&Pq[wid][l16][lhi * 8]);
    bf16x8 pfB1 = *(const bf16x8*)(&Pq[wid][l16][32 + lhi * 8]);

    // stage K(t+1)/V(t+1) into the other buffer
    if (havenext) {
      if (sg == 0) {
        *(bf16x8*)(&Kt[cur ^ 1][2 * kp][oc * 8]) = n0r;
        *(bf16x8*)(&Kt[cur ^ 1][2 * kp + 1][oc * 8]) = n1r;
      } else {
#pragma unroll
        for (int j = 0; j < 8; ++j) {
          bf16x2 pr;
          pr[0] = n0r[j];
          pr[1] = n1r[j];
          *(bf16x2*)(&Vt[cur ^ 1][oc * 8 + j][2 * kp]) = pr;
        }
      }
    }

    __builtin_amdgcn_s_setprio(1);
#pragma unroll
    for (int dt = 0; dt < 4; ++dt) {
      bf16x8 vf0 = *(const bf16x8*)(&Vt[cur][dt * 16 + l16][lhi * 8]);
      bf16x8 vf1 = *(const bf16x8*)(&Vt[cur][dt * 16 + l16][32 + lhi * 8]);
      oA[dt] = __builtin_amdgcn_mfma_f32_16x16x32_bf16(vf0, pfA0, oA[dt], 0, 0, 0);
      oA[dt] = __builtin_amdgcn_mfma_f32_16x16x32_bf16(vf1, pfA1, oA[dt], 0, 0, 0);
      oB[dt] = __builtin_amdgcn_mfma_f32_16x16x32_bf16(vf0, pfB0, oB[dt], 0, 0, 0);
      oB[dt] = __builtin_amdgcn_mfma_f32_16x16x32_bf16(vf1, pfB1, oB[dt], 0, 0, 0);
    }
    __builtin_amdgcn_s_setprio(0);

    // single barrier: retires this tile's LDS reads, publishes buffer cur^1
    __syncthreads();
  }

  {
    float l_i = lA;
    l_i += __shfl_xor(l_i, 16);
    l_i += __shfl_xor(l_i, 32);
    float rl = 1.0f / l_i;
#pragma unroll
    for (int dt = 0; dt < 4; ++dt) {
      bf16x4 ok;
#pragma unroll
      for (int r = 0; r < 4; ++r) ok[r] = (bf16)(oA[dt][r] * rl);
      *(bf16x4*)(&Pq[wid][l16][dt * 16 + lhi * 4]) = ok;
    }
    bf16x8 r0 = *(const bf16x8*)(&Pq[wid][l16][lhi * 16]);
    bf16x8 r1 = *(const bf16x8*)(&Pq[wid][l16][lhi * 16 + 8]);
    bf16* orow = qbase + (size_t)(q0 + l16) * D3 + lhi * 16;
    *(bf16x8*)(orow) = r0;
    *(bf16x8*)(orow + 8) = r1;
  }
  {
    float l_i = lB;
    l_i += __shfl_xor(l_i, 16);
    l_i += __shfl_xor(l_i, 32);
    float rl = 1.0f / l_i;
#pragma unroll
    for (int dt = 0; dt < 4; ++dt) {
      bf16x4 ok;
#pragma unroll
      for (int r = 0; r < 4; ++r) ok[r] = (bf16)(oB[dt][r] * rl);
      *(bf16x4*)(&Pq[wid][l16][dt * 16 + lhi * 4]) = ok;
    }
    bf16x8 r0 = *(const bf16x8*)(&Pq[wid][l16][lhi * 16]);
    bf16x8 r1 = *(const bf16x8*)(&Pq[wid][l16][lhi * 16 + 8]);
    bf16* orow = qbase + (size_t)(q0 + 16 + l16) * D3 + lhi * 16;
    *(bf16x8*)(orow) = r0;
    *(bf16x8*)(orow + 8) = r1;
  }
}

// ---------------------------------------------------------------------------
extern "C" void kernel_launch(void* const* d_in, const int* in_sizes, int n_in,
                              void* d_out, int out_size, void* d_ws,
                              size_t ws_size, hipStream_t stream) {
  constexpr int B = 4, S = 2048, D = 1024;

  const float* x = nullptr;
  const float* w_in = nullptr;
  const float* w_out = nullptr;
  const float* b_out = nullptr;
  for (int i = 0; i < n_in; ++i) {
    switch (in_sizes[i]) {
      case 8388608: x = (const float*)d_in[i]; break;
      case 3145728: w_in = (const float*)d_in[i]; break;
      case 1048576: w_out = (const float*)d_in[i]; break;
      case 1024: b_out = (const float*)d_in[i]; break;
    }
  }
  float* out = (float*)d_out;  // [4,2048,1024] fp32

  bf16* qkv = (bf16*)d_ws;
  const size_t need_full = (size_t)B * S * 3 * D * 2;      // 48 MiB (qkv)
  const size_t need_cvt = need_full +
                          ((size_t)B * S * D +              // x  bf16
                           (size_t)3 * D * D +              // w_in bf16
                           (size_t)D * D) * 2;              // w_out bf16

  if (ws_size >= need_cvt) {
    bf16* xb = qkv + (size_t)B * S * 3 * D;
    bf16* w_inb = xb + (size_t)B * S * D;
    bf16* w_outb = w_inb + (size_t)3 * D * D;
    const int nx8 = B * S * D / 8;
    const int nwi8 = 3 * D * D / 8;
    const int nwo8 = D * D / 8;
    cvt_bf16<<<dim3((nx8 + 255) / 256), 256, 0, stream>>>(x, xb, nx8);
    cvt_bf16<<<dim3((nwi8 + 255) / 256), 256, 0, stream>>>(w_in, w_inb, nwi8);
    cvt_bf16<<<dim3((nwo8 + 255) / 256), 256, 0, stream>>>(w_out, w_outb, nwo8);

    gemm_8ph<bf16, false><<<dim3(3 * D / 128, B * S / 256), 512, 0, stream>>>(
        xb, w_inb, nullptr, qkv, B * S, 3 * D, D, D);
    attn_fwd<<<dim3(S / 256, B * 16), 512, 0, stream>>>(qkv);
    gemm_8ph<float, true><<<dim3(D / 128, B * S / 256), 512, 0, stream>>>(
        qkv, w_outb, b_out, out, B * S, D, D, 3 * D);
  } else if (ws_size >= need_full) {
    gemm_bt<float, bf16, false><<<dim3(3 * D / 128, B * S / 128), 256, 0,
                                  stream>>>(x, w_in, nullptr, qkv, B * S,
                                            3 * D, D, D, 0);
    attn_fwd<<<dim3(S / 256, B * 16), 512, 0, stream>>>(qkv);
    gemm_bt<bf16, float, true><<<dim3(D / 128, B * S / 128), 256, 0, stream>>>(
        qkv, w_out, b_out, out, B * S, D, D, 3 * D, 0);
  } else {
    for (int b0 = 0; b0 < B; ++b0) {
      gemm_bt<float, bf16, false><<<dim3(3 * D / 128, S / 128), 256, 0,
                                    stream>>>(x, w_in, nullptr, qkv, S, 3 * D,
                                              D, D, b0 * S);
      attn_fwd<<<dim3(S / 256, 16), 512, 0, stream>>>(qkv);
      gemm_bt<bf16, float, true><<<dim3(D / 128, S / 128), 256, 0, stream>>>(
          qkv, w_out, b_out, out + (size_t)b0 * S * D, S, D, D, 3 * D, 0);
    }
  }
}

// Round 15
// 288.035 us; speedup vs baseline: 1.4363x; 1.0176x over previous
//
#include <hip/hip_runtime.h>

typedef __bf16 bf16;
typedef __bf16 bf16x2 __attribute__((ext_vector_type(2)));
typedef __bf16 bf16x4 __attribute__((ext_vector_type(4)));
typedef __bf16 bf16x8 __attribute__((ext_vector_type(8)));
typedef float f32x4 __attribute__((ext_vector_type(4)));

typedef __attribute__((address_space(1))) const unsigned int gq_t;
typedef __attribute__((address_space(3))) unsigned int lq_t;

// ---------------------------------------------------------------------------
// fp32 -> bf16 converter, 8 elems/thread.
// ---------------------------------------------------------------------------
__global__ __launch_bounds__(256) void cvt_bf16(const float* __restrict__ in,
                                                bf16* __restrict__ out,
                                                int n8) {
  int i = blockIdx.x * 256 + threadIdx.x;
  if (i >= n8) return;
  f32x4 a = ((const f32x4*)in)[2 * i];
  f32x4 b = ((const f32x4*)in)[2 * i + 1];
  bf16x8 o;
#pragma unroll
  for (int j = 0; j < 4; ++j) {
    o[j] = (bf16)a[j];
    o[4 + j] = (bf16)b[j];
  }
  ((bf16x8*)out)[i] = o;
}

// ---------------------------------------------------------------------------
// GEMM for N%192==0 shapes (G1): 256x192 tile, BK=64, 512 thr (8 waves 2Mx4N,
// wave = 128x48). r14 analysis: r13's 256x128 = 32 MFMA vs 12 ds_read + 5
// barriers per wave-tile -> 640 TF plateau. Here: 48 MFMA / 4 phases of 12;
// B-frags (6 b128) read ONCE per tile, live in regs across phases; A-frags 4
// reads/phase; 7 glds/tile all issued phases 0-1 (~2-3 phases of latency
// cover before boundary vmcnt(0)). LDS 2buf x (256+192)x64x2B = 112 KB.
// T2 both-sides swizzle + bijective XCD swizzle (nwg=512, %8==0) carried.
// Hazards: reads hit buf=g&1; glds target buf^1 whose prior reads (tile g-1)
// retired at group g-1's final barrier; boundary vmcnt(0)+barrier publishes.
// ---------------------------------------------------------------------------
template <typename TC, bool ADD_BIAS>
__global__ __launch_bounds__(512) void gemm_192(const bf16* __restrict__ A,
                                                const bf16* __restrict__ B,
                                                const float* __restrict__ bias,
                                                TC* __restrict__ C,
                                                int M, int N, int K, int lda) {
  __shared__ __align__(16) bf16 As[2][256 * 64];  // 64 KB
  __shared__ __align__(16) bf16 Bs[2][192 * 64];  // 48 KB
  const int tid = threadIdx.x;
  const int lane = tid & 63;
  const int wid = tid >> 6;       // 0..7
  const int wm = wid >> 2;        // 0..1  (M half: 128 rows)
  const int wn = wid & 3;         // 0..3  (N quarter: 48 cols)
  const int l16 = lane & 15;
  const int lhi = lane >> 4;
  const int lr = lane >> 3;       // row within 8-row chunk (0..7)

  // bijective XCD swizzle (nwg = 512, % 8 == 0)
  const int nwg = gridDim.x * gridDim.y;
  const int bid0 = blockIdx.y * gridDim.x + blockIdx.x;
  const int swzb = (bid0 & 7) * (nwg >> 3) + (bid0 >> 3);
  const int m0 = (swzb / gridDim.x) * 256;
  const int n0 = (swzb % gridDim.x) * 192;

  const int nkt = K >> 6;

  f32x4 acc[8][3] = {};

  // T2: pre-swizzled global source slot so linear glds dest = swizzled LDS.
  auto stageA = [&](int kt, int buf, int u) {
    const int chunk = wid * 4 + u;   // 32 chunks x (8 rows x 64 cols)
    const int row = chunk * 8 + lr;
    const int cs = (lane & 7) ^ lr;
    const bf16* g = A + (size_t)(m0 + row) * lda + kt * 64 + cs * 8;
    __builtin_amdgcn_global_load_lds((gq_t*)g, (lq_t*)&As[buf][chunk * 512],
                                     16, 0, 0);
  };
  auto stageB = [&](int kt, int buf, int u) {
    const int chunk = wid * 3 + u;   // 24 chunks
    const int row = chunk * 8 + lr;
    const int cs = (lane & 7) ^ lr;
    const bf16* g = B + (size_t)(n0 + row) * K + kt * 64 + cs * 8;
    __builtin_amdgcn_global_load_lds((gq_t*)g, (lq_t*)&Bs[buf][chunk * 512],
                                     16, 0, 0);
  };

  // prologue: tile 0 -> buf 0 (7 glds), drain, publish.
  stageA(0, 0, 0); stageA(0, 0, 1); stageA(0, 0, 2); stageA(0, 0, 3);
  stageB(0, 0, 0); stageB(0, 0, 1); stageB(0, 0, 2);
  asm volatile("s_waitcnt vmcnt(0)" ::: "memory");
  __builtin_amdgcn_sched_barrier(0);
  __builtin_amdgcn_s_barrier();

  for (int g = 0; g < nkt; ++g) {
    const int buf = g & 1;
    const bool donext = (g + 1) < nkt;
    const bf16* Asb = &As[buf][0];
    const bf16* Bsb = &Bs[buf][0];

    bf16x8 bfn[3][2];  // B-frags: read once (phase 0), live across phases

#pragma unroll
    for (int q = 0; q < 4; ++q) {  // 4 phases x 12 MFMA (mf pair x 3 nf x 2 ks)
      if (q == 0) {
#pragma unroll
        for (int nf = 0; nf < 3; ++nf) {
          const int nrow = wn * 48 + nf * 16 + l16;
          const int sw = nrow & 7;
#pragma unroll
          for (int ks = 0; ks < 2; ++ks) {
            const int slot = ks * 4 + lhi;
            bfn[nf][ks] =
                *(const bf16x8*)(Bsb + nrow * 64 + ((slot ^ sw) << 3));
          }
        }
      }
      bf16x8 af[2][2];
#pragma unroll
      for (int mf = 0; mf < 2; ++mf) {
        const int mrow = wm * 128 + (q * 2 + mf) * 16 + l16;
        const int sw = mrow & 7;
#pragma unroll
        for (int ks = 0; ks < 2; ++ks) {
          const int slot = ks * 4 + lhi;
          af[mf][ks] = *(const bf16x8*)(Asb + mrow * 64 + ((slot ^ sw) << 3));
        }
      }
      // issue tile g+1's glds early (phases 0-1) for max latency cover
      if (donext) {
        if (q == 0) {
          stageA(g + 1, buf ^ 1, 0);
          stageA(g + 1, buf ^ 1, 1);
          stageA(g + 1, buf ^ 1, 2);
          stageA(g + 1, buf ^ 1, 3);
        } else if (q == 1) {
          stageB(g + 1, buf ^ 1, 0);
          stageB(g + 1, buf ^ 1, 1);
          stageB(g + 1, buf ^ 1, 2);
        }
      }
      __builtin_amdgcn_s_barrier();
      asm volatile("s_waitcnt lgkmcnt(0)" ::: "memory");
      __builtin_amdgcn_sched_barrier(0);
      __builtin_amdgcn_s_setprio(1);
#pragma unroll
      for (int mf = 0; mf < 2; ++mf)
#pragma unroll
        for (int nf = 0; nf < 3; ++nf)
#pragma unroll
          for (int ks = 0; ks < 2; ++ks)
            acc[q * 2 + mf][nf] = __builtin_amdgcn_mfma_f32_16x16x32_bf16(
                af[mf][ks], bfn[nf][ks], acc[q * 2 + mf][nf], 0, 0, 0);
      __builtin_amdgcn_s_setprio(0);
      __builtin_amdgcn_s_barrier();
    }

    if (donext) {
      asm volatile("s_waitcnt vmcnt(0)" ::: "memory");
      __builtin_amdgcn_sched_barrier(0);
      __builtin_amdgcn_s_barrier();
    }
  }

  // epilogue: per-wave 128x48 block, 8x3 fragments
#pragma unroll
  for (int i = 0; i < 8; ++i) {
    int row_base = m0 + wm * 128 + i * 16 + lhi * 4;
#pragma unroll
    for (int j = 0; j < 3; ++j) {
      int col = n0 + wn * 48 + j * 16 + l16;
      float bv = ADD_BIAS ? bias[col] : 0.0f;
#pragma unroll
      for (int r = 0; r < 4; ++r) {
        float val = acc[i][j][r] + bv;
        if constexpr (__is_same(TC, float))
          C[(size_t)(row_base + r) * N + col] = val;
        else
          C[(size_t)(row_base + r) * N + col] = (bf16)val;
      }
    }
  }
}

// ---------------------------------------------------------------------------
// Pipelined bf16 GEMM 256x128 (r13 proven, T2+T3+T4) — used for G2 (N=1024):
// 256 blocks = exactly 1/CU, balanced. PARKED at ~640 TF.
// ---------------------------------------------------------------------------
template <typename TC, bool ADD_BIAS>
__global__ __launch_bounds__(512) void gemm_8ph(const bf16* __restrict__ A,
                                                const bf16* __restrict__ B,
                                                const float* __restrict__ bias,
                                                TC* __restrict__ C,
                                                int M, int N, int K, int lda) {
  __shared__ __align__(16) bf16 As[3][256 * 64];  // 96 KB
  __shared__ __align__(16) bf16 Bs[3][128 * 64];  // 48 KB
  const int tid = threadIdx.x;
  const int lane = tid & 63;
  const int wid = tid >> 6;
  const int wm = wid >> 2;
  const int wn = wid & 3;
  const int l16 = lane & 15;
  const int lhi = lane >> 4;
  const int lr = lane >> 3;

  const int nwg = gridDim.x * gridDim.y;
  const int bid0 = blockIdx.y * gridDim.x + blockIdx.x;
  const int swzb = (bid0 & 7) * (nwg >> 3) + (bid0 >> 3);
  const int m0 = (swzb / gridDim.x) * 256;
  const int n0 = (swzb % gridDim.x) * 128;

  const int nkt = K >> 6;

  f32x4 acc[8][2] = {};

  auto stageA = [&](int kt, int buf, int u) {
    const int chunk = wid * 4 + u;
    const int row = chunk * 8 + lr;
    const int cs = (lane & 7) ^ lr;
    const bf16* g = A + (size_t)(m0 + row) * lda + kt * 64 + cs * 8;
    __builtin_amdgcn_global_load_lds((gq_t*)g, (lq_t*)&As[buf][chunk * 512],
                                     16, 0, 0);
  };
  auto stageB = [&](int kt, int buf, int u) {
    const int chunk = wid * 2 + u;
    const int row = chunk * 8 + lr;
    const int cs = (lane & 7) ^ lr;
    const bf16* g = B + (size_t)(n0 + row) * K + kt * 64 + cs * 8;
    __builtin_amdgcn_global_load_lds((gq_t*)g, (lq_t*)&Bs[buf][chunk * 512],
                                     16, 0, 0);
  };

  stageA(0, 0, 0); stageA(0, 0, 1); stageA(0, 0, 2); stageA(0, 0, 3);
  stageB(0, 0, 0); stageB(0, 0, 1);
  stageA(1, 1, 0); stageA(1, 1, 1); stageA(1, 1, 2); stageA(1, 1, 3);
  stageB(1, 1, 0); stageB(1, 1, 1);
  asm volatile("s_waitcnt vmcnt(6)" ::: "memory");
  __builtin_amdgcn_sched_barrier(0);
  __builtin_amdgcn_s_barrier();

  for (int g = 0; g < nkt; ++g) {
    const int buf = g % 3;
    const int nbuf = (g + 2) % 3;
    const bool donext = (g + 2) < nkt;
    const bf16* Asb = &As[buf][0];
    const bf16* Bsb = &Bs[buf][0];

#pragma unroll
    for (int q = 0; q < 2; ++q) {
      bf16x8 af[4][2], bfn[2][2];
#pragma unroll
      for (int mf = 0; mf < 4; ++mf) {
        const int mrow = wm * 128 + (q * 4 + mf) * 16 + l16;
        const int sw = mrow & 7;
#pragma unroll
        for (int ks = 0; ks < 2; ++ks) {
          const int slot = ks * 4 + lhi;
          af[mf][ks] = *(const bf16x8*)(Asb + mrow * 64 + ((slot ^ sw) << 3));
        }
      }
#pragma unroll
      for (int nh = 0; nh < 2; ++nh) {
        const int nrow = wn * 32 + nh * 16 + l16;
        const int sw = nrow & 7;
#pragma unroll
        for (int ks = 0; ks < 2; ++ks) {
          const int slot = ks * 4 + lhi;
          bfn[nh][ks] = *(const bf16x8*)(Bsb + nrow * 64 + ((slot ^ sw) << 3));
        }
      }
      if (donext) {
        if (q == 0) {
          stageA(g + 2, nbuf, 0);
          stageA(g + 2, nbuf, 1);
          stageA(g + 2, nbuf, 2);
        } else {
          stageA(g + 2, nbuf, 3);
          stageB(g + 2, nbuf, 0);
          stageB(g + 2, nbuf, 1);
        }
      }
      __builtin_amdgcn_s_barrier();
      asm volatile("s_waitcnt lgkmcnt(0)" ::: "memory");
      __builtin_amdgcn_sched_barrier(0);
      __builtin_amdgcn_s_setprio(1);
#pragma unroll
      for (int mf = 0; mf < 4; ++mf)
#pragma unroll
        for (int nh = 0; nh < 2; ++nh)
#pragma unroll
          for (int ks = 0; ks < 2; ++ks)
            acc[q * 4 + mf][nh] = __builtin_amdgcn_mfma_f32_16x16x32_bf16(
                af[mf][ks], bfn[nh][ks], acc[q * 4 + mf][nh], 0, 0, 0);
      __builtin_amdgcn_s_setprio(0);
      __builtin_amdgcn_s_barrier();
    }

    if (g + 1 < nkt) {
      if (donext) {
        asm volatile("s_waitcnt vmcnt(6)" ::: "memory");
      } else {
        asm volatile("s_waitcnt vmcnt(0)" ::: "memory");
      }
      __builtin_amdgcn_sched_barrier(0);
      __builtin_amdgcn_s_barrier();
    }
  }

#pragma unroll
  for (int i = 0; i < 8; ++i) {
    int row_base = m0 + wm * 128 + i * 16 + lhi * 4;
#pragma unroll
    for (int j = 0; j < 2; ++j) {
      int col = n0 + wn * 32 + j * 16 + l16;
      float bv = ADD_BIAS ? bias[col] : 0.0f;
#pragma unroll
      for (int r = 0; r < 4; ++r) {
        float val = acc[i][j][r] + bv;
        if constexpr (__is_same(TC, float))
          C[(size_t)(row_base + r) * N + col] = val;
        else
          C[(size_t)(row_base + r) * N + col] = (bf16)val;
      }
    }
  }
}

// ---------------------------------------------------------------------------
// GEMM (legacy reg-staged, fp32 B): low-workspace fallback only.
// ---------------------------------------------------------------------------
template <typename TA, typename TC, bool ADD_BIAS>
__global__ __launch_bounds__(256) void gemm_bt(const TA* __restrict__ A,
                                               const float* __restrict__ B,
                                               const float* __restrict__ bias,
                                               TC* __restrict__ C,
                                               int M, int N, int K,
                                               int lda, int row0) {
  __shared__ __align__(16) bf16 As[128][72];
  __shared__ __align__(16) bf16 Bs[128][72];
  const int tid = threadIdx.x;
  const int lane = tid & 63;
  const int wid = tid >> 6;
  const int wr = wid >> 1, wc = wid & 1;
  const int m0 = blockIdx.y * 128;
  const int n0 = blockIdx.x * 128;
  const int l16 = lane & 15;
  const int lhi = lane >> 4;

  f32x4 acc[4][4] = {};

  for (int k0 = 0; k0 < K; k0 += 64) {
    __syncthreads();
#pragma unroll
    for (int p = 0; p < 8; ++p) {
      int v = tid + p * 256;
      int row = v >> 4;
      int kc = (v & 15) * 4;
      size_t ai = (size_t)(row0 + m0 + row) * lda + k0 + kc;
      size_t bi = (size_t)(n0 + row) * K + k0 + kc;
      bf16x4 ab, bb;
      if constexpr (__is_same(TA, float)) {
        f32x4 a4 = *(const f32x4*)((const float*)A + ai);
#pragma unroll
        for (int j = 0; j < 4; ++j) ab[j] = (bf16)a4[j];
      } else {
        ab = *(const bf16x4*)((const bf16*)A + ai);
      }
      f32x4 b4 = *(const f32x4*)(B + bi);
#pragma unroll
      for (int j = 0; j < 4; ++j) bb[j] = (bf16)b4[j];
      *(bf16x4*)(&As[row][kc]) = ab;
      *(bf16x4*)(&Bs[row][kc]) = bb;
    }
    __syncthreads();
#pragma unroll
    for (int ks = 0; ks < 2; ++ks) {
      bf16x8 af[4], bfr[4];
#pragma unroll
      for (int i = 0; i < 4; ++i) {
        af[i] = *(const bf16x8*)(&As[wr * 64 + i * 16 + l16][ks * 32 + lhi * 8]);
        bfr[i] = *(const bf16x8*)(&Bs[wc * 64 + i * 16 + l16][ks * 32 + lhi * 8]);
      }
#pragma unroll
      for (int i = 0; i < 4; ++i)
#pragma unroll
        for (int j = 0; j < 4; ++j)
          acc[i][j] = __builtin_amdgcn_mfma_f32_16x16x32_bf16(af[i], bfr[j],
                                                              acc[i][j], 0, 0, 0);
    }
  }

#pragma unroll
  for (int i = 0; i < 4; ++i) {
    int row_base = m0 + wr * 64 + i * 16 + lhi * 4;
#pragma unroll
    for (int j = 0; j < 4; ++j) {
      int col = n0 + wc * 64 + j * 16 + l16;
      float bv = ADD_BIAS ? bias[col] : 0.0f;
#pragma unroll
      for (int r = 0; r < 4; ++r) {
        float val = acc[i][j][r] + bv;
        if constexpr (__is_same(TC, float))
          C[(size_t)(row_base + r) * N + col] = val;
        else
          C[(size_t)(row_base + r) * N + col] = (bf16)val;
      }
    }
  }
}

// ---------------------------------------------------------------------------
// MFMA flash attention v10 (r14 proven: 119 us; unchanged).
// 8 waves/block share one Kt/Vt double-buffer; waves 0-3 stage K, 4-7 stage V.
// ---------------------------------------------------------------------------
__global__ __launch_bounds__(512) void attn_fwd(bf16* __restrict__ qkv) {
  constexpr int S = 2048, D3 = 3072;
  constexpr float SCL = 0.18033688011112042f;  // 0.125 * log2(e)
  constexpr float THR = 11.5f;                 // 8 * log2(e)
  __shared__ __align__(16) bf16 Kt[2][64][72];  // [buf][key][dim]
  __shared__ __align__(16) bf16 Vt[2][64][72];  // [buf][dim][key]
  __shared__ __align__(16) bf16 Pq[8][16][72];  // per-wave transpose buffer

  const int tid = threadIdx.x;
  const int lane = tid & 63;
  const int wid = tid >> 6;  // 0..7
  const int l16 = lane & 15, lhi = lane >> 4;

  const int nwg = gridDim.x * gridDim.y;  // 512 (full) / 128 (fallback)
  const int bid = blockIdx.y * gridDim.x + blockIdx.x;
  const int swz = (bid & 7) * (nwg >> 3) + (bid >> 3);
  const int bh = swz >> 3;
  const int b = bh >> 4, h = bh & 15;
  const int q0 = (swz & 7) * 256 + wid * 32;

  bf16* base = qkv + (size_t)b * S * D3;
  bf16* qbase = base + h * 64;
  const bf16* kbase = base + 1024 + h * 64;
  const bf16* vbase = base + 2048 + h * 64;

  bf16x8 qfA[2], qfB[2];
#pragma unroll
  for (int ks = 0; ks < 2; ++ks) {
    qfA[ks] = *(const bf16x8*)(qbase + (size_t)(q0 + l16) * D3 + ks * 32 + lhi * 8);
    qfB[ks] = *(const bf16x8*)(qbase + (size_t)(q0 + 16 + l16) * D3 + ks * 32 + lhi * 8);
  }

  float mA = -1e30f, mB = -1e30f;
  float lA = 0.0f, lB = 0.0f;
  f32x4 oA[4] = {}, oB[4] = {};

  const int sg = tid >> 8;          // 0: K, 1: V
  const int kp = tid & 31;
  const int oc = (tid >> 5) & 7;

  const bf16* sbase = (sg == 0) ? kbase : vbase;

  {
    bf16x8 s0 = *(const bf16x8*)(sbase + (size_t)(2 * kp) * D3 + oc * 8);
    bf16x8 s1 = *(const bf16x8*)(sbase + (size_t)(2 * kp + 1) * D3 + oc * 8);
    if (sg == 0) {
      *(bf16x8*)(&Kt[0][2 * kp][oc * 8]) = s0;
      *(bf16x8*)(&Kt[0][2 * kp + 1][oc * 8]) = s1;
    } else {
#pragma unroll
      for (int j = 0; j < 8; ++j) {
        bf16x2 pr;
        pr[0] = s0[j];
        pr[1] = s1[j];
        *(bf16x2*)(&Vt[0][oc * 8 + j][2 * kp]) = pr;
      }
    }
  }
  __syncthreads();

  for (int t = 0; t < S; t += 64) {
    const int cur = (t >> 6) & 1;
    const bool havenext = (t + 64 < S);

    bf16x8 n0r, n1r;
    if (havenext) {
      const bf16* sb = sbase + (size_t)(t + 64) * D3;
      n0r = *(const bf16x8*)(sb + (size_t)(2 * kp) * D3 + oc * 8);
      n1r = *(const bf16x8*)(sb + (size_t)(2 * kp + 1) * D3 + oc * 8);
    }

    f32x4 scA[4] = {}, scB[4] = {};
    __builtin_amdgcn_s_setprio(1);
#pragma unroll
    for (int ct = 0; ct < 4; ++ct) {
#pragma unroll
      for (int ks = 0; ks < 2; ++ks) {
        bf16x8 kf = *(const bf16x8*)(&Kt[cur][ct * 16 + l16][ks * 32 + lhi * 8]);
        scA[ct] = __builtin_amdgcn_mfma_f32_16x16x32_bf16(kf, qfA[ks], scA[ct], 0, 0, 0);
        scB[ct] = __builtin_amdgcn_mfma_f32_16x16x32_bf16(kf, qfB[ks], scB[ct], 0, 0, 0);
      }
    }
    __builtin_amdgcn_s_setprio(0);

    {
      float cm[4];
#pragma unroll
      for (int ct = 0; ct < 4; ++ct)
        cm[ct] = fmaxf(fmaxf(scA[ct][0], scA[ct][1]), fmaxf(scA[ct][2], scA[ct][3]));
      float mxs = fmaxf(fmaxf(cm[0], cm[1]), fmaxf(cm[2], cm[3])) * SCL;
      if (!__all(mxs - mA <= THR)) {
        float mw = mxs;
        mw = fmaxf(mw, __shfl_xor(mw, 16));
        mw = fmaxf(mw, __shfl_xor(mw, 32));
        float nm = fmaxf(mA, mw);
        float alpha = __builtin_amdgcn_exp2f(mA - nm);
        mA = nm;
        lA *= alpha;
#pragma unroll
        for (int dt = 0; dt < 4; ++dt)
#pragma unroll
          for (int r = 0; r < 4; ++r) oA[dt][r] *= alpha;
      }
      float rs4[4];
#pragma unroll
      for (int ct = 0; ct < 4; ++ct) {
#pragma unroll
        for (int r = 0; r < 4; ++r) {
          float p = __builtin_amdgcn_exp2f(__builtin_fmaf(scA[ct][r], SCL, -mA));
          scA[ct][r] = p;
        }
        rs4[ct] = (scA[ct][0] + scA[ct][1]) + (scA[ct][2] + scA[ct][3]);
      }
      lA += (rs4[0] + rs4[1]) + (rs4[2] + rs4[3]);
    }
#pragma unroll
    for (int ct = 0; ct < 4; ++ct) {
      bf16x4 pk;
#pragma unroll
      for (int r = 0; r < 4; ++r) pk[r] = (bf16)scA[ct][r];
      *(bf16x4*)(&Pq[wid][l16][ct * 16 + lhi * 4]) = pk;
    }
    bf16x8 pfA0 = *(const bf16x8*)(&Pq[wid][l16][lhi * 8]);
    bf16x8 pfA1 = *(const bf16x8*)(&Pq[wid][l16][32 + lhi * 8]);

    {
      float cm[4];
#pragma unroll
      for (int ct = 0; ct < 4; ++ct)
        cm[ct] = fmaxf(fmaxf(scB[ct][0], scB[ct][1]), fmaxf(scB[ct][2], scB[ct][3]));
      float mxs = fmaxf(fmaxf(cm[0], cm[1]), fmaxf(cm[2], cm[3])) * SCL;
      if (!__all(mxs - mB <= THR)) {
        float mw = mxs;
        mw = fmaxf(mw, __shfl_xor(mw, 16));
        mw = fmaxf(mw, __shfl_xor(mw, 32));
        float nm = fmaxf(mB, mw);
        float alpha = __builtin_amdgcn_exp2f(mB - nm);
        mB = nm;
        lB *= alpha;
#pragma unroll
        for (int dt = 0; dt < 4; ++dt)
#pragma unroll
          for (int r = 0; r < 4; ++r) oB[dt][r] *= alpha;
      }
      float rs4[4];
#pragma unroll
      for (int ct = 0; ct < 4; ++ct) {
#pragma unroll
        for (int r = 0; r < 4; ++r) {
          float p = __builtin_amdgcn_exp2f(__builtin_fmaf(scB[ct][r], SCL, -mB));
          scB[ct][r] = p;
        }
        rs4[ct] = (scB[ct][0] + scB[ct][1]) + (scB[ct][2] + scB[ct][3]);
      }
      lB += (rs4[0] + rs4[1]) + (rs4[2] + rs4[3]);
    }
#pragma unroll
    for (int ct = 0; ct < 4; ++ct) {
      bf16x4 pk;
#pragma unroll
      for (int r = 0; r < 4; ++r) pk[r] = (bf16)scB[ct][r];
      *(bf16x4*)(&Pq[wid][l16][ct * 16 + lhi * 4]) = pk;
    }
    bf16x8 pfB0 = *(const bf16x8*)(&Pq[wid][l16][lhi * 8]);
    bf16x8 pfB1 = *(const bf16x8*)(&Pq[wid][l16][32 + lhi * 8]);

    if (havenext) {
      if (sg == 0) {
        *(bf16x8*)(&Kt[cur ^ 1][2 * kp][oc * 8]) = n0r;
        *(bf16x8*)(&Kt[cur ^ 1][2 * kp + 1][oc * 8]) = n1r;
      } else {
#pragma unroll
        for (int j = 0; j < 8; ++j) {
          bf16x2 pr;
          pr[0] = n0r[j];
          pr[1] = n1r[j];
          *(bf16x2*)(&Vt[cur ^ 1][oc * 8 + j][2 * kp]) = pr;
        }
      }
    }

    __builtin_amdgcn_s_setprio(1);
#pragma unroll
    for (int dt = 0; dt < 4; ++dt) {
      bf16x8 vf0 = *(const bf16x8*)(&Vt[cur][dt * 16 + l16][lhi * 8]);
      bf16x8 vf1 = *(const bf16x8*)(&Vt[cur][dt * 16 + l16][32 + lhi * 8]);
      oA[dt] = __builtin_amdgcn_mfma_f32_16x16x32_bf16(vf0, pfA0, oA[dt], 0, 0, 0);
      oA[dt] = __builtin_amdgcn_mfma_f32_16x16x32_bf16(vf1, pfA1, oA[dt], 0, 0, 0);
      oB[dt] = __builtin_amdgcn_mfma_f32_16x16x32_bf16(vf0, pfB0, oB[dt], 0, 0, 0);
      oB[dt] = __builtin_amdgcn_mfma_f32_16x16x32_bf16(vf1, pfB1, oB[dt], 0, 0, 0);
    }
    __builtin_amdgcn_s_setprio(0);

    __syncthreads();
  }

  {
    float l_i = lA;
    l_i += __shfl_xor(l_i, 16);
    l_i += __shfl_xor(l_i, 32);
    float rl = 1.0f / l_i;
#pragma unroll
    for (int dt = 0; dt < 4; ++dt) {
      bf16x4 ok;
#pragma unroll
      for (int r = 0; r < 4; ++r) ok[r] = (bf16)(oA[dt][r] * rl);
      *(bf16x4*)(&Pq[wid][l16][dt * 16 + lhi * 4]) = ok;
    }
    bf16x8 r0 = *(const bf16x8*)(&Pq[wid][l16][lhi * 16]);
    bf16x8 r1 = *(const bf16x8*)(&Pq[wid][l16][lhi * 16 + 8]);
    bf16* orow = qbase + (size_t)(q0 + l16) * D3 + lhi * 16;
    *(bf16x8*)(orow) = r0;
    *(bf16x8*)(orow + 8) = r1;
  }
  {
    float l_i = lB;
    l_i += __shfl_xor(l_i, 16);
    l_i += __shfl_xor(l_i, 32);
    float rl = 1.0f / l_i;
#pragma unroll
    for (int dt = 0; dt < 4; ++dt) {
      bf16x4 ok;
#pragma unroll
      for (int r = 0; r < 4; ++r) ok[r] = (bf16)(oB[dt][r] * rl);
      *(bf16x4*)(&Pq[wid][l16][dt * 16 + lhi * 4]) = ok;
    }
    bf16x8 r0 = *(const bf16x8*)(&Pq[wid][l16][lhi * 16]);
    bf16x8 r1 = *(const bf16x8*)(&Pq[wid][l16][lhi * 16 + 8]);
    bf16* orow = qbase + (size_t)(q0 + 16 + l16) * D3 + lhi * 16;
    *(bf16x8*)(orow) = r0;
    *(bf16x8*)(orow + 8) = r1;
  }
}

// ---------------------------------------------------------------------------
extern "C" void kernel_launch(void* const* d_in, const int* in_sizes, int n_in,
                              void* d_out, int out_size, void* d_ws,
                              size_t ws_size, hipStream_t stream) {
  constexpr int B = 4, S = 2048, D = 1024;

  const float* x = nullptr;
  const float* w_in = nullptr;
  const float* w_out = nullptr;
  const float* b_out = nullptr;
  for (int i = 0; i < n_in; ++i) {
    switch (in_sizes[i]) {
      case 8388608: x = (const float*)d_in[i]; break;
      case 3145728: w_in = (const float*)d_in[i]; break;
      case 1048576: w_out = (const float*)d_in[i]; break;
      case 1024: b_out = (const float*)d_in[i]; break;
    }
  }
  float* out = (float*)d_out;  // [4,2048,1024] fp32

  bf16* qkv = (bf16*)d_ws;
  const size_t need_full = (size_t)B * S * 3 * D * 2;      // 48 MiB (qkv)
  const size_t need_cvt = need_full +
                          ((size_t)B * S * D +              // x  bf16
                           (size_t)3 * D * D +              // w_in bf16
                           (size_t)D * D) * 2;              // w_out bf16

  if (ws_size >= need_cvt) {
    bf16* xb = qkv + (size_t)B * S * 3 * D;
    bf16* w_inb = xb + (size_t)B * S * D;
    bf16* w_outb = w_inb + (size_t)3 * D * D;
    const int nx8 = B * S * D / 8;
    const int nwi8 = 3 * D * D / 8;
    const int nwo8 = D * D / 8;
    cvt_bf16<<<dim3((nx8 + 255) / 256), 256, 0, stream>>>(x, xb, nx8);
    cvt_bf16<<<dim3((nwi8 + 255) / 256), 256, 0, stream>>>(w_in, w_inb, nwi8);
    cvt_bf16<<<dim3((nwo8 + 255) / 256), 256, 0, stream>>>(w_out, w_outb, nwo8);

    // G1: N=3072 = 16 x 192 -> 512 blocks (2 balanced rounds, nwg%8==0)
    gemm_192<bf16, false><<<dim3(3 * D / 192, B * S / 256), 512, 0, stream>>>(
        xb, w_inb, nullptr, qkv, B * S, 3 * D, D, D);
    attn_fwd<<<dim3(S / 256, B * 16), 512, 0, stream>>>(qkv);
    // G2: N=1024 -> 256x128 tile, 256 blocks = 1/CU balanced
    gemm_8ph<float, true><<<dim3(D / 128, B * S / 256), 512, 0, stream>>>(
        qkv, w_outb, b_out, out, B * S, D, D, 3 * D);
  } else if (ws_size >= need_full) {
    gemm_bt<float, bf16, false><<<dim3(3 * D / 128, B * S / 128), 256, 0,
                                  stream>>>(x, w_in, nullptr, qkv, B * S,
                                            3 * D, D, D, 0);
    attn_fwd<<<dim3(S / 256, B * 16), 512, 0, stream>>>(qkv);
    gemm_bt<bf16, float, true><<<dim3(D / 128, B * S / 128), 256, 0, stream>>>(
        qkv, w_out, b_out, out, B * S, D, D, 3 * D, 0);
  } else {
    for (int b0 = 0; b0 < B; ++b0) {
      gemm_bt<float, bf16, false><<<dim3(3 * D / 128, S / 128), 256, 0,
                                    stream>>>(x, w_in, nullptr, qkv, S, 3 * D,
                                              D, D, b0 * S);
      attn_fwd<<<dim3(S / 256, 16), 512, 0, stream>>>(qkv);
      gemm_bt<bf16, float, true><<<dim3(D / 128, S / 128), 256, 0, stream>>>(
          qkv, w_out, b_out, out + (size_t)b0 * S * D, S, D, D, 3 * D, 0);
    }
  }
}